// Round 10
// baseline (1832.179 us; speedup 1.0000x reference)
//
#include <hip/hip_runtime.h>
#include <math.h>
#include <stdint.h>

#define TN 32768
#define C_ 256
#define E_ 524288
#define B_ 64
#define N_ 512
#define H_ 4
#define DH_ 64
#define M_ 266
#define MP_ 320
#define L_ 5
#define LN_EPS_ 1e-5f
#define EPSK_ 1e-3f

typedef short short8 __attribute__((ext_vector_type(8)));
typedef short short4v __attribute__((ext_vector_type(4)));
typedef float floatx4 __attribute__((ext_vector_type(4)));

__device__ __forceinline__ float gelu_exact(float v) {
    return 0.5f * v * (1.0f + erff(v * 0.70710678118654752f));
}

__device__ __forceinline__ short f2bf(float f) {
    union { float f; unsigned u; } v; v.f = f;
    unsigned r = v.u + 0x7FFF + ((v.u >> 16) & 1);
    return (short)(r >> 16);
}

__device__ __forceinline__ float bf2f(short s) {
    union { unsigned u; float f; } v;
    v.u = ((unsigned)(unsigned short)s) << 16;
    return v.f;
}

__device__ __forceinline__ float bflo(unsigned u) {
    union { unsigned u; float f; } v;
    v.u = u << 16;
    return v.f;
}
__device__ __forceinline__ float bfhi(unsigned u) {
    union { unsigned u; float f; } v;
    v.u = u & 0xffff0000u;
    return v.f;
}

// async global->LDS, 16B per lane, dest = lds_base + lane*16
__device__ __forceinline__ void gl2lds16(const short* g, short* l) {
    __builtin_amdgcn_global_load_lds(
        (const __attribute__((address_space(1))) unsigned int*)g,
        (__attribute__((address_space(3))) unsigned int*)l, 16, 0, 0);
}

// ---------------- embed: atoms = log(x+1) @ node_w + node_b ----------------
__global__ __launch_bounds__(256) void embed_kernel(
    const float* __restrict__ x, const float* __restrict__ nw,
    const float* __restrict__ nb, float* __restrict__ atoms,
    short* __restrict__ abf) {
    int node = blockIdx.x;
    int c = threadIdx.x;
    __shared__ float lx[11];
    if (c < 11) lx[c] = logf(x[node * 11 + c] + 1.0f);
    __syncthreads();
    float acc = nb[c];
#pragma unroll
    for (int j = 0; j < 11; ++j) acc = fmaf(lx[j], nw[j * C_ + c], acc);
    atoms[(size_t)node * C_ + c] = acc;   // fp32 copy for fallback path only
    abf[(size_t)node * C_ + c] = f2bf(acc);
}

// ----------------------- CSR build: count / scan / fill --------------------
__global__ __launch_bounds__(256) void count_kernel(const int* __restrict__ eidx,
                                                    int* __restrict__ deg) {
    int e = blockIdx.x * 256 + threadIdx.x;
    atomicAdd(&deg[eidx[E_ + e]], 1);
}

__global__ __launch_bounds__(1024) void scan_kernel(const int* __restrict__ deg,
                                                    int* __restrict__ offs,
                                                    int* __restrict__ cursor) {
    __shared__ int tsum[1024];
    int t = threadIdx.x;
    int base = t * 32;
    int local[32];
    int s = 0;
#pragma unroll
    for (int i = 0; i < 32; ++i) { local[i] = deg[base + i]; s += local[i]; }
    tsum[t] = s;
    __syncthreads();
    for (int off = 1; off < 1024; off <<= 1) {
        int v = tsum[t];
        int add = (t >= off) ? tsum[t - off] : 0;
        __syncthreads();
        tsum[t] = v + add;
        __syncthreads();
    }
    int run = tsum[t] - s;
#pragma unroll
    for (int i = 0; i < 32; ++i) {
        offs[base + i] = run;
        cursor[base + i] = run;
        run += local[i];
    }
    if (t == 1023) offs[TN] = run;
}

__global__ __launch_bounds__(256) void fill_kernel(const int* __restrict__ eidx,
                                                   const float* __restrict__ eattr,
                                                   int* __restrict__ cursor,
                                                   int* __restrict__ esrc,
                                                   float* __restrict__ easrt) {
    int e = blockIdx.x * 256 + threadIdx.x;
    int d = eidx[E_ + e];
    int pos = atomicAdd(&cursor[d], 1);
    esrc[pos] = eidx[e];
    *(float4*)(easrt + (size_t)pos * 4) = *(const float4*)(eattr + (size_t)e * 4);
}

// --- GINE gather: one WAVE per node, no barriers, all-bf16 atoms -----------
__global__ __launch_bounds__(256) void gather_kernel(
    const short* __restrict__ abf, const int* __restrict__ offs,
    const int* __restrict__ esrc, const float* __restrict__ easrt,
    const float* __restrict__ ew, const float* __restrict__ eb,
    short* __restrict__ x1bf) {
    int wv = threadIdx.x >> 6;
    int lane = threadIdx.x & 63;
    int node = blockIdx.x * 4 + wv;
    int c0 = lane * 4;
    float4 w0 = *(const float4*)(ew + c0);
    float4 w1 = *(const float4*)(ew + C_ + c0);
    float4 w2 = *(const float4*)(ew + 2 * C_ + c0);
    float4 w3 = *(const float4*)(ew + 3 * C_ + c0);
    float4 bb = *(const float4*)(eb + c0);
    int j = offs[node];
    int end = offs[node + 1];
    float4 acc = make_float4(0.f, 0.f, 0.f, 0.f);
    float4 acc2 = make_float4(0.f, 0.f, 0.f, 0.f);
    for (; j + 1 < end; j += 2) {
        int s0 = esrc[j];
        int s1 = esrc[j + 1];
        float4 e0 = *(const float4*)(easrt + (size_t)j * 4);
        float4 e1 = *(const float4*)(easrt + (size_t)(j + 1) * 4);
        uint2 p0 = *(const uint2*)(abf + (size_t)s0 * C_ + c0);
        uint2 p1 = *(const uint2*)(abf + (size_t)s1 * C_ + c0);
        float a0x = bflo(p0.x), a0y = bfhi(p0.x), a0z = bflo(p0.y), a0w = bfhi(p0.y);
        float a1x = bflo(p1.x), a1y = bfhi(p1.x), a1z = bflo(p1.y), a1w = bfhi(p1.y);
        float m;
        m = fmaf(e0.x, w0.x, fmaf(e0.y, w1.x, fmaf(e0.z, w2.x, fmaf(e0.w, w3.x, a0x + bb.x))));
        acc.x += fmaxf(m, 0.f);
        m = fmaf(e0.x, w0.y, fmaf(e0.y, w1.y, fmaf(e0.z, w2.y, fmaf(e0.w, w3.y, a0y + bb.y))));
        acc.y += fmaxf(m, 0.f);
        m = fmaf(e0.x, w0.z, fmaf(e0.y, w1.z, fmaf(e0.z, w2.z, fmaf(e0.w, w3.z, a0z + bb.z))));
        acc.z += fmaxf(m, 0.f);
        m = fmaf(e0.x, w0.w, fmaf(e0.y, w1.w, fmaf(e0.z, w2.w, fmaf(e0.w, w3.w, a0w + bb.w))));
        acc.w += fmaxf(m, 0.f);
        m = fmaf(e1.x, w0.x, fmaf(e1.y, w1.x, fmaf(e1.z, w2.x, fmaf(e1.w, w3.x, a1x + bb.x))));
        acc2.x += fmaxf(m, 0.f);
        m = fmaf(e1.x, w0.y, fmaf(e1.y, w1.y, fmaf(e1.z, w2.y, fmaf(e1.w, w3.y, a1y + bb.y))));
        acc2.y += fmaxf(m, 0.f);
        m = fmaf(e1.x, w0.z, fmaf(e1.y, w1.z, fmaf(e1.z, w2.z, fmaf(e1.w, w3.z, a1z + bb.z))));
        acc2.z += fmaxf(m, 0.f);
        m = fmaf(e1.x, w0.w, fmaf(e1.y, w1.w, fmaf(e1.z, w2.w, fmaf(e1.w, w3.w, a1w + bb.w))));
        acc2.w += fmaxf(m, 0.f);
    }
    if (j < end) {
        int s0 = esrc[j];
        float4 e0 = *(const float4*)(easrt + (size_t)j * 4);
        uint2 p0 = *(const uint2*)(abf + (size_t)s0 * C_ + c0);
        float a0x = bflo(p0.x), a0y = bfhi(p0.x), a0z = bflo(p0.y), a0w = bfhi(p0.y);
        float m;
        m = fmaf(e0.x, w0.x, fmaf(e0.y, w1.x, fmaf(e0.z, w2.x, fmaf(e0.w, w3.x, a0x + bb.x))));
        acc.x += fmaxf(m, 0.f);
        m = fmaf(e0.x, w0.y, fmaf(e0.y, w1.y, fmaf(e0.z, w2.y, fmaf(e0.w, w3.y, a0y + bb.y))));
        acc.y += fmaxf(m, 0.f);
        m = fmaf(e0.x, w0.z, fmaf(e0.y, w1.z, fmaf(e0.z, w2.z, fmaf(e0.w, w3.z, a0z + bb.z))));
        acc.z += fmaxf(m, 0.f);
        m = fmaf(e0.x, w0.w, fmaf(e0.y, w1.w, fmaf(e0.z, w2.w, fmaf(e0.w, w3.w, a0w + bb.w))));
        acc.w += fmaxf(m, 0.f);
    }
    uint2 po = *(const uint2*)(abf + (size_t)node * C_ + c0);
    short4v o;
    o.x = f2bf(bflo(po.x) + acc.x + acc2.x);
    o.y = f2bf(bfhi(po.x) + acc.y + acc2.y);
    o.z = f2bf(bflo(po.y) + acc.z + acc2.z);
    o.w = f2bf(bfhi(po.y) + acc.w + acc2.w);
    *(short4v*)(x1bf + (size_t)node * C_ + c0) = o;
}

// ------------- fallback: atomic scatter (if ws too small) ------------------
__global__ __launch_bounds__(256) void scatter_kernel(
    const float* __restrict__ atoms, const float* __restrict__ eattr,
    const int* __restrict__ eidx, const float* __restrict__ ew,
    const float* __restrict__ eb, float* __restrict__ aggr) {
    int gid = blockIdx.x * 256 + threadIdx.x;
    int e = gid >> 6;
    int q = (gid & 63) << 2;
    int src = eidx[e];
    int dst = eidx[E_ + e];
    float4 ea = *(const float4*)(eattr + (size_t)e * 4);
    float4 w0 = *(const float4*)(ew + 0 * C_ + q);
    float4 w1 = *(const float4*)(ew + 1 * C_ + q);
    float4 w2 = *(const float4*)(ew + 2 * C_ + q);
    float4 w3 = *(const float4*)(ew + 3 * C_ + q);
    float4 bb = *(const float4*)(eb + q);
    float4 av = *(const float4*)(atoms + (size_t)src * C_ + q);
    float m0 = av.x + bb.x + ea.x * w0.x + ea.y * w1.x + ea.z * w2.x + ea.w * w3.x;
    float m1 = av.y + bb.y + ea.x * w0.y + ea.y * w1.y + ea.z * w2.y + ea.w * w3.y;
    float m2 = av.z + bb.z + ea.x * w0.z + ea.y * w1.z + ea.z * w2.z + ea.w * w3.z;
    float m3 = av.w + bb.w + ea.x * w0.w + ea.y * w1.w + ea.z * w2.w + ea.w * w3.w;
    float* base = aggr + (size_t)dst * C_ + q;
    atomicAdd(base + 0, fmaxf(m0, 0.f));
    atomicAdd(base + 1, fmaxf(m1, 0.f));
    atomicAdd(base + 2, fmaxf(m2, 0.f));
    atomicAdd(base + 3, fmaxf(m3, 0.f));
}

// --- weight transpose+cast: dst[rowBase+n][k] bf16 from W[l][k][n] fp32 ----
__global__ __launch_bounds__(256) void wt_kernel(const float* __restrict__ W,
                                                 short* __restrict__ Wt,
                                                 int K, int NC,
                                                 size_t lstride, int rowBase) {
    __shared__ short tile[64][65];
    int l = blockIdx.z;
    int k0 = blockIdx.y * 64, n0 = blockIdx.x * 64;
    const float* Wl = W + (size_t)l * K * NC;
    short* Wtl = Wt + (size_t)l * lstride + (size_t)rowBase * K;
    int t = threadIdx.x;
    int rr = t >> 4;
    int cc = (t & 15) * 4;
#pragma unroll
    for (int rep = 0; rep < 4; ++rep) {
        int r = rr + rep * 16;
        float4 v = *(const float4*)(Wl + (size_t)(k0 + r) * NC + n0 + cc);
        tile[cc + 0][r] = f2bf(v.x);
        tile[cc + 1][r] = f2bf(v.y);
        tile[cc + 2][r] = f2bf(v.z);
        tile[cc + 3][r] = f2bf(v.w);
    }
    __syncthreads();
#pragma unroll
    for (int rep = 0; rep < 4; ++rep) {
        int r = rr + rep * 16;
        short4v s;
        s.x = tile[r][cc + 0];
        s.y = tile[r][cc + 1];
        s.z = tile[r][cc + 2];
        s.w = tile[r][cc + 3];
        *(short4v*)(Wtl + (size_t)(n0 + r) * K + k0 + cc) = s;
    }
}

// ---------- proj cast: Pbf[l][m][d] bf16, padded to MP_ with zeros ---------
__global__ __launch_bounds__(256) void pcast_kernel(const float* __restrict__ proj,
                                                    short* __restrict__ Pbf) {
    int l = blockIdx.x;
    for (int idx = threadIdx.x; idx < MP_ * 64; idx += 256) {
        int m = idx >> 6, d = idx & 63;
        float v = (m < M_) ? proj[(size_t)l * M_ * 64 + m * 64 + d] : 0.f;
        Pbf[(size_t)l * MP_ * 64 + idx] = f2bf(v);
    }
}

// ---------------- MFMA bf16 matmul: Y = Xbf @ Wt (+epilogue) ---------------
// EPI: 0=none, 1=gelu, 3=+R1b(bf16)
// OUT: 1=bf16 rm, 3=QKV split (NC=768: Q|K rm 256; V transposed, Yv)
template <int EPI, int OUT>
__global__ __launch_bounds__(256) void mfmm_kernel(
    const short* __restrict__ Xb, const short* __restrict__ Wt,
    const float* __restrict__ bias, const short* __restrict__ R1b,
    void* __restrict__ Yout, short* __restrict__ Yv, int K, int NC) {
    __shared__ short As[128][32];
    __shared__ short Bs[128][32];
    int tid = threadIdx.x;
    int rowBase = blockIdx.y * 128, colBase = blockIdx.x * 128;
    int lane = tid & 63;
    int wvu = __builtin_amdgcn_readfirstlane(tid >> 6);
    int wm = wvu & 1, wn = wvu >> 1;
    int quad = lane >> 4, l16 = lane & 15;
    int srow = lane >> 2;
    int sq = (lane & 3) ^ ((lane >> 3) & 3);
    int csw = ((quad ^ ((l16 >> 1) & 3)) * 8);
    const short* XpA = Xb + (size_t)(rowBase + wvu * 32 + srow) * K + sq * 8;
    const short* XpA2 = XpA + (size_t)16 * K;
    const short* WpB = Wt + (size_t)(colBase + wvu * 32 + srow) * K + sq * 8;
    const short* WpB2 = WpB + (size_t)16 * K;
    short* ldsA = &As[wvu * 32][0];
    short* ldsA2 = &As[wvu * 32 + 16][0];
    short* ldsB = &Bs[wvu * 32][0];
    short* ldsB2 = &Bs[wvu * 32 + 16][0];
    floatx4 acc[4][4];
#pragma unroll
    for (int i = 0; i < 4; ++i)
#pragma unroll
        for (int j = 0; j < 4; ++j)
            acc[i][j] = (floatx4){0.f, 0.f, 0.f, 0.f};
    for (int k0 = 0; k0 < K; k0 += 32) {
        __syncthreads();
        gl2lds16(XpA + k0, ldsA);
        gl2lds16(XpA2 + k0, ldsA2);
        gl2lds16(WpB + k0, ldsB);
        gl2lds16(WpB2 + k0, ldsB2);
        __syncthreads();
        short8 a[4], b[4];
#pragma unroll
        for (int mi = 0; mi < 4; ++mi)
            a[mi] = *(const short8*)&As[wm * 64 + mi * 16 + l16][csw];
#pragma unroll
        for (int ni = 0; ni < 4; ++ni)
            b[ni] = *(const short8*)&Bs[wn * 64 + ni * 16 + l16][csw];
#pragma unroll
        for (int mi = 0; mi < 4; ++mi)
#pragma unroll
            for (int ni = 0; ni < 4; ++ni)
                acc[mi][ni] = __builtin_amdgcn_mfma_f32_16x16x32_bf16(
                    a[mi], b[ni], acc[mi][ni], 0, 0, 0);
    }
    if (OUT == 3) {
        int region = colBase >> 8;   // 0=Q, 1=K, 2=V
        if (region < 2) {
            short* dst = (short*)Yout + (size_t)region * (size_t)TN * 256;
#pragma unroll
            for (int ni = 0; ni < 4; ++ni) {
                int cl = (colBase + wn * 64 + ni * 16 + l16) & 255;
#pragma unroll
                for (int mi = 0; mi < 4; ++mi) {
#pragma unroll
                    for (int r = 0; r < 4; ++r) {
                        int rowg = rowBase + wm * 64 + mi * 16 + quad * 4 + r;
                        dst[(size_t)rowg * 256 + cl] = f2bf(acc[mi][ni][r]);
                    }
                }
            }
        } else {
#pragma unroll
            for (int ni = 0; ni < 4; ++ni) {
                int cl = (colBase + wn * 64 + ni * 16 + l16) & 255;
                int hh = cl >> 6, dd = cl & 63;
#pragma unroll
                for (int mi = 0; mi < 4; ++mi) {
                    int rowg0 = rowBase + wm * 64 + mi * 16 + quad * 4;
                    int bb = rowg0 >> 9, ng = rowg0 & 511;
                    short4v pv;
#pragma unroll
                    for (int r = 0; r < 4; ++r) pv[r] = f2bf(acc[mi][ni][r]);
                    *(short4v*)(Yv + (((size_t)bb * 4 + hh) * 64 + dd) * 512 + ng) = pv;
                }
            }
        }
        return;
    }
#pragma unroll
    for (int ni = 0; ni < 4; ++ni) {
        int colg = colBase + wn * 64 + ni * 16 + l16;
        float bv = bias ? bias[colg] : 0.f;
#pragma unroll
        for (int mi = 0; mi < 4; ++mi) {
#pragma unroll
            for (int r = 0; r < 4; ++r) {
                int rowg = rowBase + wm * 64 + mi * 16 + quad * 4 + r;
                float y = acc[mi][ni][r] + bv;
                if (EPI == 1) y = gelu_exact(y);
                if (EPI == 3) y += bf2f(R1b[(size_t)rowg * NC + colg]);
                ((short*)Yout)[(size_t)rowg * NC + colg] = f2bf(y);
            }
        }
    }
}

// ------ MFMA matmul + fused row-LayerNorm epilogue (NC=256, 64-row tile) ---
// Y = LN(Xb@Wt + bias + Res)*g + beta  [+ Post if HAS_POST]  -> bf16
template <bool HAS_POST>
__global__ __launch_bounds__(256) void mfmm_ln_kernel(
    const short* __restrict__ Xb, const short* __restrict__ Wt,
    const float* __restrict__ bias, const short* __restrict__ Res,
    const short* __restrict__ Post, const float* __restrict__ g,
    const float* __restrict__ bta, short* __restrict__ Yout, int K) {
    __shared__ short As[64][32];
    __shared__ short Bs[256][32];
    __shared__ float redS[4][64];
    __shared__ float redS2[4][64];
    int tid = threadIdx.x;
    int rowBase = blockIdx.x * 64;
    int lane = tid & 63;
    int wvu = __builtin_amdgcn_readfirstlane(tid >> 6);
    int quad = lane >> 4, l16 = lane & 15;
    int srow = lane >> 2;
    int sq = (lane & 3) ^ ((lane >> 3) & 3);
    int csw = ((quad ^ ((l16 >> 1) & 3)) * 8);
    const short* Xp = Xb + (size_t)(rowBase + wvu * 16 + srow) * K + sq * 8;
    const short* Wp = Wt + (size_t)(wvu * 64 + srow) * K + sq * 8;
    short* ldsA = &As[wvu * 16][0];
    short* ldsB0 = &Bs[wvu * 64][0];
    short* ldsB1 = &Bs[wvu * 64 + 16][0];
    short* ldsB2 = &Bs[wvu * 64 + 32][0];
    short* ldsB3 = &Bs[wvu * 64 + 48][0];
    floatx4 acc[4][4];
#pragma unroll
    for (int i = 0; i < 4; ++i)
#pragma unroll
        for (int j = 0; j < 4; ++j)
            acc[i][j] = (floatx4){0.f, 0.f, 0.f, 0.f};
    for (int k0 = 0; k0 < K; k0 += 32) {
        __syncthreads();
        gl2lds16(Xp + k0, ldsA);
        gl2lds16(Wp + k0, ldsB0);
        gl2lds16(Wp + (size_t)16 * K + k0, ldsB1);
        gl2lds16(Wp + (size_t)32 * K + k0, ldsB2);
        gl2lds16(Wp + (size_t)48 * K + k0, ldsB3);
        __syncthreads();
        short8 a[4], b[4];
#pragma unroll
        for (int mi = 0; mi < 4; ++mi)
            a[mi] = *(const short8*)&As[mi * 16 + l16][csw];
#pragma unroll
        for (int ni = 0; ni < 4; ++ni)
            b[ni] = *(const short8*)&Bs[wvu * 64 + ni * 16 + l16][csw];
#pragma unroll
        for (int mi = 0; mi < 4; ++mi)
#pragma unroll
            for (int ni = 0; ni < 4; ++ni)
                acc[mi][ni] = __builtin_amdgcn_mfma_f32_16x16x32_bf16(
                    a[mi], b[ni], acc[mi][ni], 0, 0, 0);
    }
    // ---- epilogue: bias + residual, row stats, LN ----
    int cols[4];
    float gv[4], bv[4], biasv[4];
#pragma unroll
    for (int ni = 0; ni < 4; ++ni) {
        cols[ni] = wvu * 64 + ni * 16 + l16;
        gv[ni] = g[cols[ni]];
        bv[ni] = bta[cols[ni]];
        biasv[ni] = bias[cols[ni]];
    }
    float ps[4][4], ps2[4][4];
#pragma unroll
    for (int mi = 0; mi < 4; ++mi)
#pragma unroll
        for (int r = 0; r < 4; ++r) { ps[mi][r] = 0.f; ps2[mi][r] = 0.f; }
#pragma unroll
    for (int mi = 0; mi < 4; ++mi) {
#pragma unroll
        for (int r = 0; r < 4; ++r) {
            size_t rowg = rowBase + mi * 16 + quad * 4 + r;
#pragma unroll
            for (int ni = 0; ni < 4; ++ni) {
                float y = acc[mi][ni][r] + biasv[ni] +
                          bf2f(Res[rowg * 256 + cols[ni]]);
                acc[mi][ni][r] = y;
                ps[mi][r] += y;
                ps2[mi][r] += y * y;
            }
        }
    }
#pragma unroll
    for (int mask = 1; mask < 16; mask <<= 1) {
#pragma unroll
        for (int mi = 0; mi < 4; ++mi)
#pragma unroll
            for (int r = 0; r < 4; ++r) {
                ps[mi][r] += __shfl_xor(ps[mi][r], mask);
                ps2[mi][r] += __shfl_xor(ps2[mi][r], mask);
            }
    }
    __syncthreads();
    if (l16 == 0) {
#pragma unroll
        for (int mi = 0; mi < 4; ++mi)
#pragma unroll
            for (int r = 0; r < 4; ++r) {
                redS[wvu][mi * 16 + quad * 4 + r] = ps[mi][r];
                redS2[wvu][mi * 16 + quad * 4 + r] = ps2[mi][r];
            }
    }
    __syncthreads();
#pragma unroll
    for (int mi = 0; mi < 4; ++mi) {
#pragma unroll
        for (int r = 0; r < 4; ++r) {
            int rl = mi * 16 + quad * 4 + r;
            float s = redS[0][rl] + redS[1][rl] + redS[2][rl] + redS[3][rl];
            float s2 = redS2[0][rl] + redS2[1][rl] + redS2[2][rl] + redS2[3][rl];
            float mu = s * (1.f / 256.f);
            float var = s2 * (1.f / 256.f) - mu * mu;
            float inv = rsqrtf(var + LN_EPS_);
            size_t rowg = rowBase + rl;
#pragma unroll
            for (int ni = 0; ni < 4; ++ni) {
                float y = (acc[mi][ni][r] - mu) * inv * gv[ni] + bv[ni];
                if (HAS_POST) y += bf2f(Post[rowg * 256 + cols[ni]]);
                Yout[rowg * 256 + cols[ni]] = f2bf(y);
            }
        }
    }
}

// ------ fused GINE MLP: HL = LN1(gelu(X1@W1+b1)@W2 + b2 + Res) -------------
// 64-row block; t1 lives in LDS (64x256 bf16, pitch 264).
__global__ __launch_bounds__(256) void gmlp_kernel(
    const short* __restrict__ X1, const short* __restrict__ W1t,
    const float* __restrict__ b1, const short* __restrict__ W2t,
    const float* __restrict__ b2, const short* __restrict__ Res,
    const float* __restrict__ g, const float* __restrict__ bta,
    short* __restrict__ Yout) {
    __shared__ short As[64][32];
    __shared__ short Bs[256][32];
    __shared__ short Tb[64][264];
    __shared__ float redS[4][64];
    __shared__ float redS2[4][64];
    int tid = threadIdx.x;
    int rowBase = blockIdx.x * 64;
    int lane = tid & 63;
    int wvu = __builtin_amdgcn_readfirstlane(tid >> 6);
    int quad = lane >> 4, l16 = lane & 15;
    int srow = lane >> 2;
    int sq = (lane & 3) ^ ((lane >> 3) & 3);
    int csw = ((quad ^ ((l16 >> 1) & 3)) * 8);
    const short* Xp = X1 + (size_t)(rowBase + wvu * 16 + srow) * 256 + sq * 8;
    const short* W1p = W1t + (size_t)(wvu * 64 + srow) * 256 + sq * 8;
    const short* W2p = W2t + (size_t)(wvu * 64 + srow) * 256 + sq * 8;
    short* ldsA = &As[wvu * 16][0];
    short* ldsB0 = &Bs[wvu * 64][0];
    short* ldsB1 = &Bs[wvu * 64 + 16][0];
    short* ldsB2 = &Bs[wvu * 64 + 32][0];
    short* ldsB3 = &Bs[wvu * 64 + 48][0];
    floatx4 acc[4][4];
#pragma unroll
    for (int i = 0; i < 4; ++i)
#pragma unroll
        for (int j = 0; j < 4; ++j)
            acc[i][j] = (floatx4){0.f, 0.f, 0.f, 0.f};
    // phase 1: t1 = gelu(X1 @ W1 + b1)
    for (int k0 = 0; k0 < 256; k0 += 32) {
        __syncthreads();
        gl2lds16(Xp + k0, ldsA);
        gl2lds16(W1p + k0, ldsB0);
        gl2lds16(W1p + 16 * 256 + k0, ldsB1);
        gl2lds16(W1p + 32 * 256 + k0, ldsB2);
        gl2lds16(W1p + 48 * 256 + k0, ldsB3);
        __syncthreads();
        short8 a[4], b[4];
#pragma unroll
        for (int mi = 0; mi < 4; ++mi)
            a[mi] = *(const short8*)&As[mi * 16 + l16][csw];
#pragma unroll
        for (int ni = 0; ni < 4; ++ni)
            b[ni] = *(const short8*)&Bs[wvu * 64 + ni * 16 + l16][csw];
#pragma unroll
        for (int mi = 0; mi < 4; ++mi)
#pragma unroll
            for (int ni = 0; ni < 4; ++ni)
                acc[mi][ni] = __builtin_amdgcn_mfma_f32_16x16x32_bf16(
                    a[mi], b[ni], acc[mi][ni], 0, 0, 0);
    }
#pragma unroll
    for (int ni = 0; ni < 4; ++ni) {
        int col = wvu * 64 + ni * 16 + l16;
        float bv1 = b1[col];
#pragma unroll
        for (int mi = 0; mi < 4; ++mi)
#pragma unroll
            for (int r = 0; r < 4; ++r)
                Tb[mi * 16 + quad * 4 + r][col] =
                    f2bf(gelu_exact(acc[mi][ni][r] + bv1));
    }
#pragma unroll
    for (int i = 0; i < 4; ++i)
#pragma unroll
        for (int j = 0; j < 4; ++j)
            acc[i][j] = (floatx4){0.f, 0.f, 0.f, 0.f};
    // phase 2: acc = t1 @ W2
    for (int k0 = 0; k0 < 256; k0 += 32) {
        __syncthreads();
        gl2lds16(W2p + k0, ldsB0);
        gl2lds16(W2p + 16 * 256 + k0, ldsB1);
        gl2lds16(W2p + 32 * 256 + k0, ldsB2);
        gl2lds16(W2p + 48 * 256 + k0, ldsB3);
        __syncthreads();
        short8 a[4], b[4];
#pragma unroll
        for (int mi = 0; mi < 4; ++mi)
            a[mi] = *(const short8*)&Tb[mi * 16 + l16][k0 + quad * 8];
#pragma unroll
        for (int ni = 0; ni < 4; ++ni)
            b[ni] = *(const short8*)&Bs[wvu * 64 + ni * 16 + l16][csw];
#pragma unroll
        for (int mi = 0; mi < 4; ++mi)
#pragma unroll
            for (int ni = 0; ni < 4; ++ni)
                acc[mi][ni] = __builtin_amdgcn_mfma_f32_16x16x32_bf16(
                    a[mi], b[ni], acc[mi][ni], 0, 0, 0);
    }
    // LN epilogue
    int cols[4];
    float gv[4], bv[4], biasv[4];
#pragma unroll
    for (int ni = 0; ni < 4; ++ni) {
        cols[ni] = wvu * 64 + ni * 16 + l16;
        gv[ni] = g[cols[ni]];
        bv[ni] = bta[cols[ni]];
        biasv[ni] = b2[cols[ni]];
    }
    float ps[4][4], ps2[4][4];
#pragma unroll
    for (int mi = 0; mi < 4; ++mi)
#pragma unroll
        for (int r = 0; r < 4; ++r) { ps[mi][r] = 0.f; ps2[mi][r] = 0.f; }
#pragma unroll
    for (int mi = 0; mi < 4; ++mi) {
#pragma unroll
        for (int r = 0; r < 4; ++r) {
            size_t rowg = rowBase + mi * 16 + quad * 4 + r;
#pragma unroll
            for (int ni = 0; ni < 4; ++ni) {
                float y = acc[mi][ni][r] + biasv[ni] +
                          bf2f(Res[rowg * 256 + cols[ni]]);
                acc[mi][ni][r] = y;
                ps[mi][r] += y;
                ps2[mi][r] += y * y;
            }
        }
    }
#pragma unroll
    for (int mask = 1; mask < 16; mask <<= 1) {
#pragma unroll
        for (int mi = 0; mi < 4; ++mi)
#pragma unroll
            for (int r = 0; r < 4; ++r) {
                ps[mi][r] += __shfl_xor(ps[mi][r], mask);
                ps2[mi][r] += __shfl_xor(ps2[mi][r], mask);
            }
    }
    __syncthreads();
    if (l16 == 0) {
#pragma unroll
        for (int mi = 0; mi < 4; ++mi)
#pragma unroll
            for (int r = 0; r < 4; ++r) {
                redS[wvu][mi * 16 + quad * 4 + r] = ps[mi][r];
                redS2[wvu][mi * 16 + quad * 4 + r] = ps2[mi][r];
            }
    }
    __syncthreads();
#pragma unroll
    for (int mi = 0; mi < 4; ++mi) {
#pragma unroll
        for (int r = 0; r < 4; ++r) {
            int rl = mi * 16 + quad * 4 + r;
            float s = redS[0][rl] + redS[1][rl] + redS[2][rl] + redS[3][rl];
            float s2 = redS2[0][rl] + redS2[1][rl] + redS2[2][rl] + redS2[3][rl];
            float mu = s * (1.f / 256.f);
            float var = s2 * (1.f / 256.f) - mu * mu;
            float inv = rsqrtf(var + LN_EPS_);
            size_t rowg = rowBase + rl;
#pragma unroll
            for (int ni = 0; ni < 4; ++ni) {
                float y = (acc[mi][ni][r] - mu) * inv * gv[ni] + bv[ni];
                Yout[rowg * 256 + cols[ni]] = f2bf(y);
            }
        }
    }
}

// ------ fused FFN: Abf = LN3(gelu(SUM@W1+b1)@W2 + b2 + SUM) ----------------
// 64-row block; t2 processed in two 256-col halves resident in LDS.
__global__ __launch_bounds__(256) void ffn_kernel(
    const short* __restrict__ SUM, const short* __restrict__ W1t,
    const float* __restrict__ b1, const short* __restrict__ W2t,
    const float* __restrict__ b2, const float* __restrict__ g,
    const float* __restrict__ bta, short* __restrict__ Yout) {
    __shared__ short As[64][32];
    __shared__ short Bs[256][32];
    __shared__ short Tb[64][264];
    __shared__ float redS[4][64];
    __shared__ float redS2[4][64];
    int tid = threadIdx.x;
    int rowBase = blockIdx.x * 64;
    int lane = tid & 63;
    int wvu = __builtin_amdgcn_readfirstlane(tid >> 6);
    int quad = lane >> 4, l16 = lane & 15;
    int srow = lane >> 2;
    int sq = (lane & 3) ^ ((lane >> 3) & 3);
    int csw = ((quad ^ ((l16 >> 1) & 3)) * 8);
    const short* Xp = SUM + (size_t)(rowBase + wvu * 16 + srow) * 256 + sq * 8;
    short* ldsA = &As[wvu * 16][0];
    short* ldsB0 = &Bs[wvu * 64][0];
    short* ldsB1 = &Bs[wvu * 64 + 16][0];
    short* ldsB2 = &Bs[wvu * 64 + 32][0];
    short* ldsB3 = &Bs[wvu * 64 + 48][0];
    floatx4 acc2[4][4];
#pragma unroll
    for (int i = 0; i < 4; ++i)
#pragma unroll
        for (int j = 0; j < 4; ++j)
            acc2[i][j] = (floatx4){0.f, 0.f, 0.f, 0.f};
    for (int h = 0; h < 2; ++h) {
        const short* W1p = W1t + (size_t)(h * 256 + wvu * 64 + srow) * 256 + sq * 8;
        const short* W2p = W2t + (size_t)(wvu * 64 + srow) * 512 + h * 256 + sq * 8;
        floatx4 acc1[4][4];
#pragma unroll
        for (int i = 0; i < 4; ++i)
#pragma unroll
            for (int j = 0; j < 4; ++j)
                acc1[i][j] = (floatx4){0.f, 0.f, 0.f, 0.f};
        // phase 1: t2h = gelu(SUM @ W1[h] + b1[h])
        for (int k0 = 0; k0 < 256; k0 += 32) {
            __syncthreads();
            gl2lds16(Xp + k0, ldsA);
            gl2lds16(W1p + k0, ldsB0);
            gl2lds16(W1p + 16 * 256 + k0, ldsB1);
            gl2lds16(W1p + 32 * 256 + k0, ldsB2);
            gl2lds16(W1p + 48 * 256 + k0, ldsB3);
            __syncthreads();
            short8 a[4], b[4];
#pragma unroll
            for (int mi = 0; mi < 4; ++mi)
                a[mi] = *(const short8*)&As[mi * 16 + l16][csw];
#pragma unroll
            for (int ni = 0; ni < 4; ++ni)
                b[ni] = *(const short8*)&Bs[wvu * 64 + ni * 16 + l16][csw];
#pragma unroll
            for (int mi = 0; mi < 4; ++mi)
#pragma unroll
                for (int ni = 0; ni < 4; ++ni)
                    acc1[mi][ni] = __builtin_amdgcn_mfma_f32_16x16x32_bf16(
                        a[mi], b[ni], acc1[mi][ni], 0, 0, 0);
        }
        __syncthreads();   // separate prior Tb reads (h=1) / none (h=0) from writes
#pragma unroll
        for (int ni = 0; ni < 4; ++ni) {
            int col = wvu * 64 + ni * 16 + l16;
            float bv1 = b1[h * 256 + col];
#pragma unroll
            for (int mi = 0; mi < 4; ++mi)
#pragma unroll
                for (int r = 0; r < 4; ++r)
                    Tb[mi * 16 + quad * 4 + r][col] =
                        f2bf(gelu_exact(acc1[mi][ni][r] + bv1));
        }
        // phase 2: acc2 += t2h @ W2[:, h*256:...]
        for (int k0 = 0; k0 < 256; k0 += 32) {
            __syncthreads();
            gl2lds16(W2p + k0, ldsB0);
            gl2lds16(W2p + (size_t)16 * 512 + k0, ldsB1);
            gl2lds16(W2p + (size_t)32 * 512 + k0, ldsB2);
            gl2lds16(W2p + (size_t)48 * 512 + k0, ldsB3);
            __syncthreads();
            short8 a[4], b[4];
#pragma unroll
            for (int mi = 0; mi < 4; ++mi)
                a[mi] = *(const short8*)&Tb[mi * 16 + l16][k0 + quad * 8];
#pragma unroll
            for (int ni = 0; ni < 4; ++ni)
                b[ni] = *(const short8*)&Bs[wvu * 64 + ni * 16 + l16][csw];
#pragma unroll
            for (int mi = 0; mi < 4; ++mi)
#pragma unroll
                for (int ni = 0; ni < 4; ++ni)
                    acc2[mi][ni] = __builtin_amdgcn_mfma_f32_16x16x32_bf16(
                        a[mi], b[ni], acc2[mi][ni], 0, 0, 0);
        }
    }
    // LN epilogue with Res = SUM
    int cols[4];
    float gv[4], bv[4], biasv[4];
#pragma unroll
    for (int ni = 0; ni < 4; ++ni) {
        cols[ni] = wvu * 64 + ni * 16 + l16;
        gv[ni] = g[cols[ni]];
        bv[ni] = bta[cols[ni]];
        biasv[ni] = b2[cols[ni]];
    }
    float ps[4][4], ps2[4][4];
#pragma unroll
    for (int mi = 0; mi < 4; ++mi)
#pragma unroll
        for (int r = 0; r < 4; ++r) { ps[mi][r] = 0.f; ps2[mi][r] = 0.f; }
#pragma unroll
    for (int mi = 0; mi < 4; ++mi) {
#pragma unroll
        for (int r = 0; r < 4; ++r) {
            size_t rowg = rowBase + mi * 16 + quad * 4 + r;
#pragma unroll
            for (int ni = 0; ni < 4; ++ni) {
                float y = acc2[mi][ni][r] + biasv[ni] +
                          bf2f(SUM[rowg * 256 + cols[ni]]);
                acc2[mi][ni][r] = y;
                ps[mi][r] += y;
                ps2[mi][r] += y * y;
            }
        }
    }
#pragma unroll
    for (int mask = 1; mask < 16; mask <<= 1) {
#pragma unroll
        for (int mi = 0; mi < 4; ++mi)
#pragma unroll
            for (int r = 0; r < 4; ++r) {
                ps[mi][r] += __shfl_xor(ps[mi][r], mask);
                ps2[mi][r] += __shfl_xor(ps2[mi][r], mask);
            }
    }
    __syncthreads();
    if (l16 == 0) {
#pragma unroll
        for (int mi = 0; mi < 4; ++mi)
#pragma unroll
            for (int r = 0; r < 4; ++r) {
                redS[wvu][mi * 16 + quad * 4 + r] = ps[mi][r];
                redS2[wvu][mi * 16 + quad * 4 + r] = ps2[mi][r];
            }
    }
    __syncthreads();
#pragma unroll
    for (int mi = 0; mi < 4; ++mi) {
#pragma unroll
        for (int r = 0; r < 4; ++r) {
            int rl = mi * 16 + quad * 4 + r;
            float s = redS[0][rl] + redS[1][rl] + redS[2][rl] + redS[3][rl];
            float s2 = redS2[0][rl] + redS2[1][rl] + redS2[2][rl] + redS2[3][rl];
            float mu = s * (1.f / 256.f);
            float var = s2 * (1.f / 256.f) - mu * mu;
            float inv = rsqrtf(var + LN_EPS_);
            size_t rowg = rowBase + rl;
#pragma unroll
            for (int ni = 0; ni < 4; ++ni) {
                float y = (acc2[mi][ni][r] - mu) * inv * gv[ni] + bv[ni];
                Yout[rowg * 256 + cols[ni]] = f2bf(y);
            }
        }
    }
}

// ------------- fallback fp32 tiled matmul (old path) -----------------------
template <bool IN_ADD, int EPI>
__global__ __launch_bounds__(256) void mm_kernel(
    const float* __restrict__ X, const float* __restrict__ X2,
    const float* __restrict__ W, const float* __restrict__ bias,
    const float* __restrict__ R1, const float* __restrict__ R2,
    float* __restrict__ Y, int K, int NC) {
    __shared__ float Xs[16][65];
    __shared__ float Ws[16][68];
    int tid = threadIdx.x;
    int tx = tid & 15, ty = tid >> 4;
    int rowBase = blockIdx.y * 64;
    int colBase = blockIdx.x * 64;
    int lr = tid >> 2;
    int lk = (tid & 3) << 2;
    int wk = tid >> 4;
    int wc = (tid & 15) << 2;
    const float* Xp = X + (size_t)(rowBase + lr) * K + lk;
    const float* X2p = IN_ADD ? (X2 + (size_t)(rowBase + lr) * K + lk) : X;
    const float* Wp = W + (size_t)wk * NC + colBase + wc;
    float acc[4][4] = {};
    for (int k0 = 0; k0 < K; k0 += 16) {
        float4 xv = *(const float4*)(Xp + k0);
        if (IN_ADD) {
            float4 x2 = *(const float4*)(X2p + k0);
            xv.x += x2.x; xv.y += x2.y; xv.z += x2.z; xv.w += x2.w;
        }
        float4 wv = *(const float4*)(Wp + (size_t)k0 * NC);
        __syncthreads();
        Xs[lk + 0][lr] = xv.x;
        Xs[lk + 1][lr] = xv.y;
        Xs[lk + 2][lr] = xv.z;
        Xs[lk + 3][lr] = xv.w;
        *(float4*)&Ws[wk][wc] = wv;
        __syncthreads();
#pragma unroll
        for (int kk = 0; kk < 16; ++kk) {
            float a[4], b[4];
#pragma unroll
            for (int i = 0; i < 4; ++i) a[i] = Xs[kk][ty * 4 + i];
#pragma unroll
            for (int j = 0; j < 4; ++j) b[j] = Ws[kk][tx * 4 + j];
#pragma unroll
            for (int i = 0; i < 4; ++i)
#pragma unroll
                for (int j = 0; j < 4; ++j) acc[i][j] = fmaf(a[i], b[j], acc[i][j]);
        }
    }
    int c0 = colBase + tx * 4;
    float4 bv = make_float4(0.f, 0.f, 0.f, 0.f);
    if (bias) bv = *(const float4*)(bias + c0);
#pragma unroll
    for (int i = 0; i < 4; ++i) {
        int r = rowBase + ty * 4 + i;
        float4 y;
        y.x = acc[i][0] + bv.x; y.y = acc[i][1] + bv.y;
        y.z = acc[i][2] + bv.z; y.w = acc[i][3] + bv.w;
        if (EPI == 1) {
            y.x = gelu_exact(y.x); y.y = gelu_exact(y.y);
            y.z = gelu_exact(y.z); y.w = gelu_exact(y.w);
        }
        if (EPI >= 2) {
            float4 r1 = *(const float4*)(R1 + (size_t)r * NC + c0);
            y.x += r1.x; y.y += r1.y; y.z += r1.z; y.w += r1.w;
        }
        if (EPI == 3) {
            float4 r2 = *(const float4*)(R2 + (size_t)r * NC + c0);
            y.x += r2.x; y.y += r2.y; y.z += r2.z; y.w += r2.w;
        }
        *(float4*)(Y + (size_t)r * NC + c0) = y;
    }
}

// fp32 LN fallback
__global__ __launch_bounds__(256) void ln_kernel(
    const float* __restrict__ X, const float* __restrict__ g,
    const float* __restrict__ bta, float* __restrict__ Y) {
    __shared__ float rs[4], rs2[4];
    __shared__ float mu_s, inv_s;
    int row = blockIdx.x, t = threadIdx.x;
    size_t off = (size_t)row * C_ + t;
    float v = X[off];
    float s = v, s2 = v * v;
#pragma unroll
    for (int o = 32; o > 0; o >>= 1) {
        s += __shfl_down(s, o);
        s2 += __shfl_down(s2, o);
    }
    int w = t >> 6, lane = t & 63;
    if (lane == 0) { rs[w] = s; rs2[w] = s2; }
    __syncthreads();
    if (t == 0) {
        float tot = rs[0] + rs[1] + rs[2] + rs[3];
        float tot2 = rs2[0] + rs2[1] + rs2[2] + rs2[3];
        float mu = tot * (1.f / C_);
        float var = tot2 * (1.f / C_) - mu * mu;
        mu_s = mu;
        inv_s = rsqrtf(var + LN_EPS_);
    }
    __syncthreads();
    Y[off] = (v - mu_s) * inv_s * g[t] + bta[t];
}

// ---------- MFMA Performer pass 1: ctxT[bh][d][m], ksum[bh][m] -------------
__global__ __launch_bounds__(256) void p1m_kernel(
    const short* __restrict__ Kbf, const short* __restrict__ VbfT,
    const short* __restrict__ Pbf, short* __restrict__ ctxT,
    float* __restrict__ ksum) {
    int mt = blockIdx.x;
    int bh = blockIdx.y;
    int b = bh >> 2, h = bh & 3;
    __shared__ short Ps[64][72];
    __shared__ short Ks[64][72];
    __shared__ short VTs[64][72];
    __shared__ short Ss[64][72];
    __shared__ float kred[4][64];
    int tid = threadIdx.x;
    int w = tid >> 6, lane = tid & 63;
    int quad = lane >> 4, l16 = lane & 15;
    int lr = tid >> 2, lb = (tid & 3) << 4;
    {
        const short* p = Pbf + ((size_t)(mt * 64 + lr)) * 64 + lb;
        *(short8*)&Ps[lr][lb] = *(const short8*)p;
        *(short8*)&Ps[lr][lb + 8] = *(const short8*)(p + 8);
    }
    floatx4 cacc[4];
#pragma unroll
    for (int i = 0; i < 4; ++i) cacc[i] = (floatx4){0.f, 0.f, 0.f, 0.f};
    float kacc[4] = {0.f, 0.f, 0.f, 0.f};
    size_t kbase = ((size_t)(b * 512)) * 256 + h * 64;
    size_t vbase = ((size_t)(bh * 64)) * 512;
    for (int nt = 0; nt < 8; ++nt) {
        __syncthreads();
        {
            const short* kp = Kbf + kbase + (size_t)(nt * 64 + lr) * 256 + lb;
            *(short8*)&Ks[lr][lb] = *(const short8*)kp;
            *(short8*)&Ks[lr][lb + 8] = *(const short8*)(kp + 8);
            const short* vp = VbfT + vbase + (size_t)lr * 512 + nt * 64 + lb;
            *(short8*)&VTs[lr][lb] = *(const short8*)vp;
            *(short8*)&VTs[lr][lb + 8] = *(const short8*)(vp + 8);
        }
        __syncthreads();
        floatx4 sa[4];
#pragma unroll
        for (int mi = 0; mi < 4; ++mi) sa[mi] = (floatx4){0.f, 0.f, 0.f, 0.f};
#pragma unroll
        for (int kt = 0; kt < 2; ++kt) {
            short8 a = *(const short8*)&Ks[w * 16 + l16][kt * 32 + quad * 8];
#pragma unroll
            for (int mi = 0; mi < 4; ++mi) {
                short8 bq = *(const short8*)&Ps[mi * 16 + l16][kt * 32 + quad * 8];
                sa[mi] = __builtin_amdgcn_mfma_f32_16x16x32_bf16(a, bq, sa[mi], 0, 0, 0);
            }
        }
#pragma unroll
        for (int mi = 0; mi < 4; ++mi) {
            int mg = mt * 64 + mi * 16 + l16;
            short4v sv;
            float kl = 0.f;
#pragma unroll
            for (int r = 0; r < 4; ++r) {
                float v = (mg < M_) ? (fmaxf(sa[mi][r], 0.f) + EPSK_) : 0.f;
                sv[r] = f2bf(v);
                kl += v;
            }
            kacc[mi] += kl;
            *(short4v*)&Ss[mi * 16 + l16][w * 16 + quad * 4] = sv;
        }
        __syncthreads();
#pragma unroll
        for (int kt = 0; kt < 2; ++kt) {
            short8 a = *(const short8*)&Ss[w * 16 + l16][kt * 32 + quad * 8];
#pragma unroll
            for (int di = 0; di < 4; ++di) {
                short8 bv = *(const short8*)&VTs[di * 16 + l16][kt * 32 + quad * 8];
                cacc[di] = __builtin_amdgcn_mfma_f32_16x16x32_bf16(a, bv, cacc[di], 0, 0, 0);
            }
        }
    }
    size_t cbase = ((size_t)bh * 64) * MP_ + mt * 64;
#pragma unroll
    for (int di = 0; di < 4; ++di) {
        int d = di * 16 + l16;
        short4v cv;
#pragma unroll
        for (int r = 0; r < 4; ++r) cv[r] = f2bf(cacc[di][r]);
        *(short4v*)(ctxT + cbase + (size_t)d * MP_ + w * 16 + quad * 4) = cv;
    }
#pragma unroll
    for (int mi = 0; mi < 4; ++mi) {
        kacc[mi] += __shfl_down(kacc[mi], 32);
        kacc[mi] += __shfl_down(kacc[mi], 16);
    }
    if (lane < 16) {
#pragma unroll
        for (int mi = 0; mi < 4; ++mi) kred[w][mi * 16 + lane] = kacc[mi];
    }
    __syncthreads();
    if (tid < 64)
        ksum[(size_t)bh * MP_ + mt * 64 + tid] =
            kred[0][tid] + kred[1][tid] + kred[2][tid] + kred[3][tid];
}

// ---------- MFMA Performer pass 2: attbf = bf16((qp@ctx)/(qp@ksum)) --------
__global__ __launch_bounds__(256) void p2m_kernel(
    const short* __restrict__ Qbf, const short* __restrict__ Pbf,
    const short* __restrict__ ctxT, const float* __restrict__ ksum,
    short* __restrict__ attbf) {
    int nt = blockIdx.x;
    int bh = blockIdx.y;
    int b = bh >> 2, h = bh & 3;
    __shared__ short Qs[64][72];
    __shared__ short Ps[64][72];
    __shared__ short CTs[64][72];
    __shared__ short Ss[64][72];
    __shared__ float kss[64];
    __shared__ float dredS[64];
    __shared__ float dinvS[64];
    int tid = threadIdx.x;
    int w = tid >> 6, lane = tid & 63;
    int quad = lane >> 4, l16 = lane & 15;
    int lr = tid >> 2, lb = (tid & 3) << 4;
    size_t qbase = ((size_t)(b * 512)) * 256 + h * 64;
    {
        const short* qp = Qbf + qbase + (size_t)(nt * 64 + lr) * 256 + lb;
        *(short8*)&Qs[lr][lb] = *(const short8*)qp;
        *(short8*)&Qs[lr][lb + 8] = *(const short8*)(qp + 8);
    }
    floatx4 aacc[4];
#pragma unroll
    for (int i = 0; i < 4; ++i) aacc[i] = (floatx4){0.f, 0.f, 0.f, 0.f};
    float dd[4] = {0.f, 0.f, 0.f, 0.f};
    size_t cb = ((size_t)bh * 64) * MP_;
    for (int mt = 0; mt < 5; ++mt) {
        __syncthreads();
        {
            const short* p = Pbf + ((size_t)(mt * 64 + lr)) * 64 + lb;
            *(short8*)&Ps[lr][lb] = *(const short8*)p;
            *(short8*)&Ps[lr][lb + 8] = *(const short8*)(p + 8);
            const short* cp = ctxT + cb + (size_t)lr * MP_ + mt * 64 + lb;
            *(short8*)&CTs[lr][lb] = *(const short8*)cp;
            *(short8*)&CTs[lr][lb + 8] = *(const short8*)(cp + 8);
        }
        if (tid < 64) kss[tid] = ksum[(size_t)bh * MP_ + mt * 64 + tid];
        __syncthreads();
        floatx4 sa[4];
#pragma unroll
        for (int mi = 0; mi < 4; ++mi) sa[mi] = (floatx4){0.f, 0.f, 0.f, 0.f};
#pragma unroll
        for (int kt = 0; kt < 2; ++kt) {
            short8 a = *(const short8*)&Qs[w * 16 + l16][kt * 32 + quad * 8];
#pragma unroll
            for (int mi = 0; mi < 4; ++mi) {
                short8 bq = *(const short8*)&Ps[mi * 16 + l16][kt * 32 + quad * 8];
                sa[mi] = __builtin_amdgcn_mfma_f32_16x16x32_bf16(a, bq, sa[mi], 0, 0, 0);
            }
        }
#pragma unroll
        for (int mi = 0; mi < 4; ++mi) {
            int mg = mt * 64 + mi * 16 + l16;
            float ksv = kss[mi * 16 + l16];
#pragma unroll
            for (int r = 0; r < 4; ++r) {
                float v = (mg < M_) ? (fmaxf(sa[mi][r], 0.f) + EPSK_) : 0.f;
                Ss[w * 16 + quad * 4 + r][mi * 16 + l16] = f2bf(v);
                dd[r] += v * ksv;
            }
        }
        __syncthreads();
#pragma unroll
        for (int kt = 0; kt < 2; ++kt) {
            short8 a = *(const short8*)&Ss[w * 16 + l16][kt * 32 + quad * 8];
#pragma unroll
            for (int di = 0; di < 4; ++di) {
                short8 bv = *(const short8*)&CTs[di * 16 + l16][kt * 32 + quad * 8];
                aacc[di] = __builtin_amdgcn_mfma_f32_16x16x32_bf16(a, bv, aacc[di], 0, 0, 0);
            }
        }
    }
#pragma unroll
    for (int r = 0; r < 4; ++r) {
        dd[r] += __shfl_xor(dd[r], 1);
        dd[r] += __shfl_xor(dd[r], 2);
        dd[r] += __shfl_xor(dd[r], 4);
        dd[r] += __shfl_xor(dd[r], 8);
    }
    if (l16 == 0) {
#pragma unroll
        for (int r = 0; r < 4; ++r) dredS[w * 16 + quad * 4 + r] = dd[r];
    }
    __syncthreads();
    if (tid < 64) dinvS[tid] = 1.f / dredS[tid];
    __syncthreads();
#pragma unroll
    for (int di = 0; di < 4; ++di) {
        int d = di * 16 + l16;
#pragma unroll
        for (int r = 0; r < 4; ++r) {
            int n = w * 16 + quad * 4 + r;
            attbf[((size_t)(b * 512 + nt * 64 + n)) * 256 + h * 64 + d] =
                f2bf(aacc[di][r] * dinvS[n]);
        }
    }
}

// ---------------- fp32 Performer fallbacks (old path) ----------------------
__global__ __launch_bounds__(256) void p1_kernel(
    const float* __restrict__ kbuf, const float* __restrict__ vbuf,
    const float* __restrict__ proj, float* __restrict__ ctx,
    float* __restrict__ ksum) {
    int mt = blockIdx.x;
    int bh = blockIdx.y;
    int b = bh >> 2, h = bh & 3;
    __shared__ float Pt[64][65];
    __shared__ float KV[64][65];
    __shared__ float S[64][65];
    int tid = threadIdx.x;
    int tx = tid & 15, ty = tid >> 4;
    for (int idx = tid; idx < 4096; idx += 256) {
        int r = idx >> 6, c = idx & 63;
        int mg = mt * 64 + r;
        Pt[r][c] = (mg < M_) ? proj[mg * DH_ + c] : 0.f;
    }
    float cacc[4][4] = {};
    float ksacc = 0.f;
    size_t base = ((size_t)b * N_) * C_ + h * DH_;
    for (int nt = 0; nt < 8; ++nt) {
        __syncthreads();
        for (int idx = tid; idx < 4096; idx += 256) {
            int r = idx >> 6, c = idx & 63;
            KV[r][c] = kbuf[base + (size_t)(nt * 64 + r) * C_ + c];
        }
        __syncthreads();
        float s[4][4] = {};
        for (int dd = 0; dd < 64; ++dd) {
            float a[4], bq[4];
#pragma unroll
            for (int i = 0; i < 4; ++i) a[i] = KV[ty * 4 + i][dd];
#pragma unroll
            for (int j = 0; j < 4; ++j) bq[j] = Pt[16 * j + tx][dd];
#pragma unroll
            for (int i = 0; i < 4; ++i)
#pragma unroll
                for (int j = 0; j < 4; ++j) s[i][j] = fmaf(a[i], bq[j], s[i][j]);
        }
        __syncthreads();
#pragma unroll
        for (int i = 0; i < 4; ++i)
#pragma unroll
            for (int j = 0; j < 4; ++j) {
                int mg = mt * 64 + 16 * j + tx;
                S[ty * 4 + i][16 * j + tx] =
                    (mg < M_) ? (fmaxf(s[i][j], 0.f) + EPSK_) : 0.f;
            }
        for (int idx = tid; idx < 4096; idx += 256) {
            int r = idx >> 6, c = idx & 63;
            KV[r][c] = vbuf[base + (size_t)(nt * 64 + r) * C_ + c];
        }
        __syncthreads();
        for (int nn = 0; nn < 64; ++nn) {
            float sm[4], vd[4];
#pragma unroll
            for (int i = 0; i < 4; ++i) sm[i] = S[nn][ty * 4 + i];
#pragma unroll
            for (int j = 0; j < 4; ++j) vd[j] = KV[nn][tx * 4 + j];
#pragma unroll
            for (int i = 0; i < 4; ++i)
#pragma unroll
                for (int j = 0; j < 4; ++j) cacc[i][j] = fmaf(sm[i], vd[j], cacc[i][j]);
        }
        if (tid < 64) {
            for (int nn = 0; nn < 64; ++nn) ksacc += S[nn][tid];
        }
    }
    float* cp = ctx + ((size_t)bh * MP_ + mt * 64) * DH_;
#pragma unroll
    for (int i = 0; i < 4; ++i)
#pragma unroll
        for (int j = 0; j < 4; ++j)
            cp[(ty * 4 + i) * DH_ + tx * 4 + j] = cacc[i][j];
    if (tid < 64) ksum[bh * MP_ + mt * 64 + tid] = ksacc;
}

__global__ __launch_bounds__(256) void p2_kernel(
    const float* __restrict__ qbuf, const float* __restrict__ proj,
    const float* __restrict__ ctx, const float* __restrict__ ksum,
    float* __restrict__ attout) {
    int nt = blockIdx.x;
    int bh = blockIdx.y;
    int b = bh >> 2, h = bh & 3;
    __shared__ float Qt[64][65];
    __shared__ float PC[64][65];
    __shared__ float S[64][65];
    __shared__ float ks[64], dinv[64];
    int tid = threadIdx.x;
    int tx = tid & 15, ty = tid >> 4;
    size_t base = ((size_t)b * N_) * C_ + h * DH_;
    for (int idx = tid; idx < 4096; idx += 256) {
        int r = idx >> 6, c = idx & 63;
        Qt[r][c] = qbuf[base + (size_t)(nt * 64 + r) * C_ + c];
    }
    float aacc[4][4] = {};
    float dacc = 0.f;
    for (int mt = 0; mt < 5; ++mt) {
        __syncthreads();
        for (int idx = tid; idx < 4096; idx += 256) {
            int r = idx >> 6, c = idx & 63;
            int mg = mt * 64 + r;
            PC[r][c] = (mg < M_) ? proj[mg * DH_ + c] : 0.f;
        }
        if (tid < 64) ks[tid] = ksum[bh * MP_ + mt * 64 + tid];
        __syncthreads();
        float s[4][4] = {};
        for (int dd = 0; dd < 64; ++dd) {
            float a[4], bq[4];
#pragma unroll
            for (int i = 0; i < 4; ++i) a[i] = Qt[ty * 4 + i][dd];
#pragma unroll
            for (int j = 0; j < 4; ++j) bq[j] = PC[16 * j + tx][dd];
#pragma unroll
            for (int i = 0; i < 4; ++i)
#pragma unroll
                for (int j = 0; j < 4; ++j) s[i][j] = fmaf(a[i], bq[j], s[i][j]);
        }
        __syncthreads();
#pragma unroll
        for (int i = 0; i < 4; ++i)
#pragma unroll
            for (int j = 0; j < 4; ++j) {
                int mg = mt * 64 + 16 * j + tx;
                S[ty * 4 + i][16 * j + tx] =
                    (mg < M_) ? (fmaxf(s[i][j], 0.f) + EPSK_) : 0.f;
            }
        for (int idx = tid; idx < 4096; idx += 256) {
            int r = idx >> 6, c = idx & 63;
            PC[r][c] = ctx[((size_t)bh * MP_ + mt * 64 + r) * DH_ + c];
        }
        __syncthreads();
        for (int mm = 0; mm < 64; ++mm) {
            float sm[4], cd[4];
#pragma unroll
            for (int i = 0; i < 4; ++i) sm[i] = S[ty * 4 + i][mm];
#pragma unroll
            for (int j = 0; j < 4; ++j) cd[j] = PC[mm][tx * 4 + j];
#pragma unroll
            for (int i = 0; i < 4; ++i)
#pragma unroll
                for (int j = 0; j < 4; ++j) aacc[i][j] = fmaf(sm[i], cd[j], aacc[i][j]);
        }
        if (tid < 64) {
            for (int mm = 0; mm < 64; ++mm) dacc = fmaf(S[tid][mm], ks[mm], dacc);
        }
    }
    __syncthreads();
    if (tid < 64) dinv[tid] = 1.f / dacc;
    __syncthreads();
#pragma unroll
    for (int i = 0; i < 4; ++i) {
        int n = ty * 4 + i;
        float di = dinv[n];
        float4 y = make_float4(aacc[i][0] * di, aacc[i][1] * di,
                               aacc[i][2] * di, aacc[i][3] * di);
        *(float4*)(attout + base + (size_t)(nt * 64 + n) * C_ + tx * 4) = y;
    }
}

// -------------------- mean pool (bf16 in, fp32 out) ------------------------
__global__ __launch_bounds__(256) void pool_kernel(const short* __restrict__ abf,
                                                   float* __restrict__ out) {
    int b = blockIdx.x;
    int c = threadIdx.x;
    const short* p = abf + (size_t)b * N_ * C_ + c;
    float s = 0.f;
    for (int n = 0; n < N_; ++n) s += bf2f(p[(size_t)n * C_]);
    out[b * C_ + c] = s * (1.f / 512.f);
}

__global__ __launch_bounds__(256) void poolf_kernel(const float* __restrict__ atoms,
                                                    float* __restrict__ out) {
    int b = blockIdx.x;
    int c = threadIdx.x;
    const float* p = atoms + (size_t)b * N_ * C_ + c;
    float s = 0.f;
    for (int n = 0; n < N_; ++n) s += p[(size_t)n * C_];
    out[b * C_ + c] = s * (1.f / 512.f);
}

extern "C" void kernel_launch(void* const* d_in, const int* in_sizes, int n_in,
                              void* d_out, int out_size, void* d_ws, size_t ws_size,
                              hipStream_t stream) {
    (void)in_sizes; (void)n_in; (void)out_size;
    const float* x = (const float*)d_in[0];
    const float* edge_attr = (const float*)d_in[1];
    const int* edge_index = (const int*)d_in[2];
    const float* node_w = (const float*)d_in[4];
    const float* node_b = (const float*)d_in[5];
    const float* edge_w = (const float*)d_in[6];
    const float* edge_b = (const float*)d_in[7];
    const float* gine_w1 = (const float*)d_in[8];
    const float* gine_b1 = (const float*)d_in[9];
    const float* gine_w2 = (const float*)d_in[10];
    const float* gine_b2 = (const float*)d_in[11];
    const float* q_w = (const float*)d_in[12];
    const float* k_w = (const float*)d_in[13];
    const float* v_w = (const float*)d_in[14];
    const float* o_w = (const float*)d_in[15];
    const float* o_b = (const float*)d_in[16];
    const float* proj = (const float*)d_in[17];
    const float* n1g = (const float*)d_in[18];
    const float* n1b = (const float*)d_in[19];
    const float* n2g = (const float*)d_in[20];
    const float* n2b = (const float*)d_in[21];
    const float* n3g = (const float*)d_in[22];
    const float* n3b = (const float*)d_in[23];
    const float* mw1 = (const float*)d_in[24];
    const float* mb1 = (const float*)d_in[25];
    const float* mw2 = (const float*)d_in[26];
    const float* mb2 = (const float*)d_in[27];

    const size_t SZ = (size_t)TN * C_;   // 8,388,608
    float* ws = (float*)d_ws;
    float* A     = ws;                               // fp32 atoms (fallback only)
    short* Abf   = (short*)(ws + SZ);
    short* X1bf  = (short*)(ws + SZ + SZ / 2);
    short* ATTbf = (short*)(ws + 2 * SZ);
    short* HLbf  = (short*)(ws + 2 * SZ + SZ / 2);
    short* Qbf   = (short*)(ws + 3 * SZ);
    short* Kbf   = (short*)(ws + 3 * SZ + SZ / 2);
    short* VbfT  = (short*)(ws + 4 * SZ);
    short* ctxTb = (short*)(ws + 4 * SZ + SZ / 2);
    float* KS2   = (float*)(ctxTb + (size_t)256 * 64 * MP_);
    short* SUMbf = (short*)(ws + 5 * SZ);

    int* deg    = (int*)(ws + 6 * SZ);
    int* offs   = deg + TN;
    int* cursor = offs + TN + 1;
    int* esrc   = cursor + TN;
    float* easrt = (float*)(((uintptr_t)(esrc + E_) + 15) & ~(uintptr_t)15);
    short* WTg1  = (short*)(easrt + (size_t)4 * E_);
    short* WTg2  = WTg1 + (size_t)5 * 65536;
    short* WTqkv = WTg2 + (size_t)5 * 65536;
    short* WTo   = WTqkv + (size_t)5 * 196608;
    short* WTm1  = WTo + (size_t)5 * 65536;
    short* WTm2  = WTm1 + (size_t)5 * 131072;
    short* Pbf   = WTm2 + (size_t)5 * 131072;
    size_t need = 6 * SZ * sizeof(float) +
                  (size_t)(3 * TN + 1 + E_) * sizeof(int) + 16 +
                  (size_t)4 * E_ * sizeof(float) +
                  ((size_t)5 * (3 * 65536 + 196608 + 2 * 131072 + MP_ * 64)) *
                      sizeof(short);
    bool full = ws_size >= need;

    dim3 gm768(6, 256);
    dim3 g256(4, 512), g512(8, 512);

    embed_kernel<<<TN, 256, 0, stream>>>(x, node_w, node_b, A, Abf);
    if (full) {
        hipMemsetAsync(deg, 0, TN * sizeof(int), stream);
        count_kernel<<<E_ / 256, 256, 0, stream>>>(edge_index, deg);
        scan_kernel<<<1, 1024, 0, stream>>>(deg, offs, cursor);
        fill_kernel<<<E_ / 256, 256, 0, stream>>>(edge_index, edge_attr, cursor,
                                                  esrc, easrt);
        wt_kernel<<<dim3(4, 4, L_), 256, 0, stream>>>(gine_w1, WTg1, 256, 256, 65536, 0);
        wt_kernel<<<dim3(4, 4, L_), 256, 0, stream>>>(gine_w2, WTg2, 256, 256, 65536, 0);
        wt_kernel<<<dim3(4, 4, L_), 256, 0, stream>>>(q_w, WTqkv, 256, 256, 196608, 0);
        wt_kernel<<<dim3(4, 4, L_), 256, 0, stream>>>(k_w, WTqkv, 256, 256, 196608, 256);
        wt_kernel<<<dim3(4, 4, L_), 256, 0, stream>>>(v_w, WTqkv, 256, 256, 196608, 512);
        wt_kernel<<<dim3(4, 4, L_), 256, 0, stream>>>(o_w, WTo, 256, 256, 65536, 0);
        wt_kernel<<<dim3(8, 4, L_), 256, 0, stream>>>(mw1, WTm1, 256, 512, 131072, 0);
        wt_kernel<<<dim3(4, 8, L_), 256, 0, stream>>>(mw2, WTm2, 512, 256, 131072, 0);
        pcast_kernel<<<L_, 256, 0, stream>>>(proj, Pbf);
    }
    for (int l = 0; l < L_; ++l) {
        if (full) {
            gather_kernel<<<TN / 4, 256, 0, stream>>>(Abf, offs, esrc, easrt,
                                                      edge_w, edge_b, X1bf);
            // HL = LN1(gelu(X1@g1+b1)@g2 + b2 + Abf)   [fully fused]
            gmlp_kernel<<<TN / 64, 256, 0, stream>>>(
                X1bf, WTg1 + (size_t)l * 65536, gine_b1 + l * 256,
                WTg2 + (size_t)l * 65536, gine_b2 + l * 256,
                Abf, n1g + l * 256, n1b + l * 256, HLbf);
            // QKV fused
            mfmm_kernel<0, 3><<<gm768, 256, 0, stream>>>(
                Abf, WTqkv + (size_t)l * 196608, nullptr,
                nullptr, Qbf, VbfT, 256, 768);
            p1m_kernel<<<dim3(5, 256), 256, 0, stream>>>(
                Kbf, VbfT, Pbf + (size_t)l * MP_ * 64, ctxTb, KS2);
            p2m_kernel<<<dim3(8, 256), 256, 0, stream>>>(
                Qbf, Pbf + (size_t)l * MP_ * 64, ctxTb, KS2, ATTbf);
            // SUM = LN2(ATT @ o_w + o_b + Abf) + HL   [fused]
            mfmm_ln_kernel<true><<<TN / 64, 256, 0, stream>>>(
                ATTbf, WTo + (size_t)l * 65536, o_b + l * 256,
                Abf, HLbf, n2g + l * 256, n2b + l * 256, SUMbf, 256);
            // Abf = LN3(gelu(SUM@m1+b1)@m2 + b2 + SUM)   [fully fused]
            ffn_kernel<<<TN / 64, 256, 0, stream>>>(
                SUMbf, WTm1 + (size_t)l * 131072, mb1 + l * 512,
                WTm2 + (size_t)l * 131072, mb2 + l * 256,
                n3g + l * 256, n3b + l * 256, Abf);
        } else {
            float* AGf = A + SZ;
            float* Tf = AGf + SZ;
            float* HLf = Tf + 2 * SZ;
            float* Vbf2 = HLf + SZ;
            float* Qf = AGf;
            float* Kf = Tf;
            float* CTXf = Tf + SZ;
            float* KSf = CTXf + (size_t)256 * MP_ * DH_;
            hipMemsetAsync(AGf, 0, SZ * sizeof(float), stream);
            scatter_kernel<<<E_ * 64 / 256, 256, 0, stream>>>(A, edge_attr, edge_index,
                                                              edge_w, edge_b, AGf);
            mm_kernel<true, 1><<<g256, 256, 0, stream>>>(A, AGf, gine_w1 + l * 65536,
                                                         gine_b1 + l * 256, nullptr,
                                                         nullptr, Tf, 256, 256);
            mm_kernel<false, 2><<<g256, 256, 0, stream>>>(Tf, nullptr, gine_w2 + l * 65536,
                                                          gine_b2 + l * 256, A, nullptr,
                                                          HLf, 256, 256);
            ln_kernel<<<TN, 256, 0, stream>>>(HLf, n1g + l * 256, n1b + l * 256, HLf);
            mm_kernel<false, 0><<<g256, 256, 0, stream>>>(A, nullptr, q_w + l * 65536,
                                                          nullptr, nullptr, nullptr,
                                                          Qf, 256, 256);
            mm_kernel<false, 0><<<g256, 256, 0, stream>>>(A, nullptr, k_w + l * 65536,
                                                          nullptr, nullptr, nullptr,
                                                          Kf, 256, 256);
            mm_kernel<false, 0><<<g256, 256, 0, stream>>>(A, nullptr, v_w + l * 65536,
                                                          nullptr, nullptr, nullptr,
                                                          Vbf2, 256, 256);
            p1_kernel<<<dim3(5, 256), 256, 0, stream>>>(Kf, Vbf2, proj + l * (M_ * DH_),
                                                        CTXf, KSf);
            p2_kernel<<<dim3(8, 256), 256, 0, stream>>>(Qf, proj + l * (M_ * DH_),
                                                        CTXf, KSf, Kf);
            mm_kernel<false, 2><<<g256, 256, 0, stream>>>(Kf, nullptr, o_w + l * 65536,
                                                          o_b + l * 256, A, nullptr,
                                                          Qf, 256, 256);
            ln_kernel<<<TN, 256, 0, stream>>>(Qf, n2g + l * 256, n2b + l * 256, Qf);
            mm_kernel<true, 1><<<g512, 256, 0, stream>>>(HLf, Qf, mw1 + l * 131072,
                                                         mb1 + l * 512, nullptr, nullptr,
                                                         Tf, 256, 512);
            mm_kernel<false, 3><<<g256, 256, 0, stream>>>(Tf, nullptr, mw2 + l * 131072,
                                                          mb2 + l * 256, HLf, Qf,
                                                          Vbf2, 512, 256);
            ln_kernel<<<TN, 256, 0, stream>>>(Vbf2, n3g + l * 256, n3b + l * 256, A);
        }
    }
    if (full)
        pool_kernel<<<B_, 256, 0, stream>>>(Abf, (float*)d_out);
    else
        poolf_kernel<<<B_, 256, 0, stream>>>(A, (float*)d_out);
}

// Round 11
// 1698.236 us; speedup vs baseline: 1.0789x; 1.0789x over previous
//
#include <hip/hip_runtime.h>
#include <math.h>
#include <stdint.h>

#define TN 32768
#define C_ 256
#define E_ 524288
#define B_ 64
#define N_ 512
#define H_ 4
#define DH_ 64
#define M_ 266
#define MP_ 320
#define L_ 5
#define LN_EPS_ 1e-5f
#define EPSK_ 1e-3f

typedef short short8 __attribute__((ext_vector_type(8)));
typedef short short4v __attribute__((ext_vector_type(4)));
typedef float floatx4 __attribute__((ext_vector_type(4)));

__device__ __forceinline__ float gelu_exact(float v) {
    return 0.5f * v * (1.0f + erff(v * 0.70710678118654752f));
}

__device__ __forceinline__ short f2bf(float f) {
    union { float f; unsigned u; } v; v.f = f;
    unsigned r = v.u + 0x7FFF + ((v.u >> 16) & 1);
    return (short)(r >> 16);
}

__device__ __forceinline__ float bf2f(short s) {
    union { unsigned u; float f; } v;
    v.u = ((unsigned)(unsigned short)s) << 16;
    return v.f;
}

__device__ __forceinline__ float bflo(unsigned u) {
    union { unsigned u; float f; } v;
    v.u = u << 16;
    return v.f;
}
__device__ __forceinline__ float bfhi(unsigned u) {
    union { unsigned u; float f; } v;
    v.u = u & 0xffff0000u;
    return v.f;
}

// async global->LDS, 16B per lane, dest = lds_base + lane*16
__device__ __forceinline__ void gl2lds16(const short* g, short* l) {
    __builtin_amdgcn_global_load_lds(
        (const __attribute__((address_space(1))) unsigned int*)g,
        (__attribute__((address_space(3))) unsigned int*)l, 16, 0, 0);
}

// ---------------- embed: atoms = log(x+1) @ node_w + node_b ----------------
__global__ __launch_bounds__(256) void embed_kernel(
    const float* __restrict__ x, const float* __restrict__ nw,
    const float* __restrict__ nb, float* __restrict__ atoms,
    short* __restrict__ abf) {
    int node = blockIdx.x;
    int c = threadIdx.x;
    __shared__ float lx[11];
    if (c < 11) lx[c] = logf(x[node * 11 + c] + 1.0f);
    __syncthreads();
    float acc = nb[c];
#pragma unroll
    for (int j = 0; j < 11; ++j) acc = fmaf(lx[j], nw[j * C_ + c], acc);
    atoms[(size_t)node * C_ + c] = acc;   // fp32 copy for fallback path only
    abf[(size_t)node * C_ + c] = f2bf(acc);
}

// ----------------------- CSR build: count / scan / fill --------------------
__global__ __launch_bounds__(256) void count_kernel(const int* __restrict__ eidx,
                                                    int* __restrict__ deg) {
    int e = blockIdx.x * 256 + threadIdx.x;
    atomicAdd(&deg[eidx[E_ + e]], 1);
}

__global__ __launch_bounds__(1024) void scan_kernel(const int* __restrict__ deg,
                                                    int* __restrict__ offs,
                                                    int* __restrict__ cursor) {
    __shared__ int tsum[1024];
    int t = threadIdx.x;
    int base = t * 32;
    int local[32];
    int s = 0;
#pragma unroll
    for (int i = 0; i < 32; ++i) { local[i] = deg[base + i]; s += local[i]; }
    tsum[t] = s;
    __syncthreads();
    for (int off = 1; off < 1024; off <<= 1) {
        int v = tsum[t];
        int add = (t >= off) ? tsum[t - off] : 0;
        __syncthreads();
        tsum[t] = v + add;
        __syncthreads();
    }
    int run = tsum[t] - s;
#pragma unroll
    for (int i = 0; i < 32; ++i) {
        offs[base + i] = run;
        cursor[base + i] = run;
        run += local[i];
    }
    if (t == 1023) offs[TN] = run;
}

__global__ __launch_bounds__(256) void fill_kernel(const int* __restrict__ eidx,
                                                   const float* __restrict__ eattr,
                                                   int* __restrict__ cursor,
                                                   int* __restrict__ esrc,
                                                   float* __restrict__ easrt) {
    int e = blockIdx.x * 256 + threadIdx.x;
    int d = eidx[E_ + e];
    int pos = atomicAdd(&cursor[d], 1);
    esrc[pos] = eidx[e];
    *(float4*)(easrt + (size_t)pos * 4) = *(const float4*)(eattr + (size_t)e * 4);
}

// --- GINE gather: one WAVE per node, no barriers, all-bf16 atoms -----------
__global__ __launch_bounds__(256) void gather_kernel(
    const short* __restrict__ abf, const int* __restrict__ offs,
    const int* __restrict__ esrc, const float* __restrict__ easrt,
    const float* __restrict__ ew, const float* __restrict__ eb,
    short* __restrict__ x1bf) {
    int wv = threadIdx.x >> 6;
    int lane = threadIdx.x & 63;
    int node = blockIdx.x * 4 + wv;
    int c0 = lane * 4;
    float4 w0 = *(const float4*)(ew + c0);
    float4 w1 = *(const float4*)(ew + C_ + c0);
    float4 w2 = *(const float4*)(ew + 2 * C_ + c0);
    float4 w3 = *(const float4*)(ew + 3 * C_ + c0);
    float4 bb = *(const float4*)(eb + c0);
    int j = offs[node];
    int end = offs[node + 1];
    float4 acc = make_float4(0.f, 0.f, 0.f, 0.f);
    float4 acc2 = make_float4(0.f, 0.f, 0.f, 0.f);
    for (; j + 1 < end; j += 2) {
        int s0 = esrc[j];
        int s1 = esrc[j + 1];
        float4 e0 = *(const float4*)(easrt + (size_t)j * 4);
        float4 e1 = *(const float4*)(easrt + (size_t)(j + 1) * 4);
        uint2 p0 = *(const uint2*)(abf + (size_t)s0 * C_ + c0);
        uint2 p1 = *(const uint2*)(abf + (size_t)s1 * C_ + c0);
        float a0x = bflo(p0.x), a0y = bfhi(p0.x), a0z = bflo(p0.y), a0w = bfhi(p0.y);
        float a1x = bflo(p1.x), a1y = bfhi(p1.x), a1z = bflo(p1.y), a1w = bfhi(p1.y);
        float m;
        m = fmaf(e0.x, w0.x, fmaf(e0.y, w1.x, fmaf(e0.z, w2.x, fmaf(e0.w, w3.x, a0x + bb.x))));
        acc.x += fmaxf(m, 0.f);
        m = fmaf(e0.x, w0.y, fmaf(e0.y, w1.y, fmaf(e0.z, w2.y, fmaf(e0.w, w3.y, a0y + bb.y))));
        acc.y += fmaxf(m, 0.f);
        m = fmaf(e0.x, w0.z, fmaf(e0.y, w1.z, fmaf(e0.z, w2.z, fmaf(e0.w, w3.z, a0z + bb.z))));
        acc.z += fmaxf(m, 0.f);
        m = fmaf(e0.x, w0.w, fmaf(e0.y, w1.w, fmaf(e0.z, w2.w, fmaf(e0.w, w3.w, a0w + bb.w))));
        acc.w += fmaxf(m, 0.f);
        m = fmaf(e1.x, w0.x, fmaf(e1.y, w1.x, fmaf(e1.z, w2.x, fmaf(e1.w, w3.x, a1x + bb.x))));
        acc2.x += fmaxf(m, 0.f);
        m = fmaf(e1.x, w0.y, fmaf(e1.y, w1.y, fmaf(e1.z, w2.y, fmaf(e1.w, w3.y, a1y + bb.y))));
        acc2.y += fmaxf(m, 0.f);
        m = fmaf(e1.x, w0.z, fmaf(e1.y, w1.z, fmaf(e1.z, w2.z, fmaf(e1.w, w3.z, a1z + bb.z))));
        acc2.z += fmaxf(m, 0.f);
        m = fmaf(e1.x, w0.w, fmaf(e1.y, w1.w, fmaf(e1.z, w2.w, fmaf(e1.w, w3.w, a1w + bb.w))));
        acc2.w += fmaxf(m, 0.f);
    }
    if (j < end) {
        int s0 = esrc[j];
        float4 e0 = *(const float4*)(easrt + (size_t)j * 4);
        uint2 p0 = *(const uint2*)(abf + (size_t)s0 * C_ + c0);
        float a0x = bflo(p0.x), a0y = bfhi(p0.x), a0z = bflo(p0.y), a0w = bfhi(p0.y);
        float m;
        m = fmaf(e0.x, w0.x, fmaf(e0.y, w1.x, fmaf(e0.z, w2.x, fmaf(e0.w, w3.x, a0x + bb.x))));
        acc.x += fmaxf(m, 0.f);
        m = fmaf(e0.x, w0.y, fmaf(e0.y, w1.y, fmaf(e0.z, w2.y, fmaf(e0.w, w3.y, a0y + bb.y))));
        acc.y += fmaxf(m, 0.f);
        m = fmaf(e0.x, w0.z, fmaf(e0.y, w1.z, fmaf(e0.z, w2.z, fmaf(e0.w, w3.z, a0z + bb.z))));
        acc.z += fmaxf(m, 0.f);
        m = fmaf(e0.x, w0.w, fmaf(e0.y, w1.w, fmaf(e0.z, w2.w, fmaf(e0.w, w3.w, a0w + bb.w))));
        acc.w += fmaxf(m, 0.f);
    }
    uint2 po = *(const uint2*)(abf + (size_t)node * C_ + c0);
    short4v o;
    o.x = f2bf(bflo(po.x) + acc.x + acc2.x);
    o.y = f2bf(bfhi(po.x) + acc.y + acc2.y);
    o.z = f2bf(bflo(po.y) + acc.z + acc2.z);
    o.w = f2bf(bfhi(po.y) + acc.w + acc2.w);
    *(short4v*)(x1bf + (size_t)node * C_ + c0) = o;
}

// ------------- fallback: atomic scatter (if ws too small) ------------------
__global__ __launch_bounds__(256) void scatter_kernel(
    const float* __restrict__ atoms, const float* __restrict__ eattr,
    const int* __restrict__ eidx, const float* __restrict__ ew,
    const float* __restrict__ eb, float* __restrict__ aggr) {
    int gid = blockIdx.x * 256 + threadIdx.x;
    int e = gid >> 6;
    int q = (gid & 63) << 2;
    int src = eidx[e];
    int dst = eidx[E_ + e];
    float4 ea = *(const float4*)(eattr + (size_t)e * 4);
    float4 w0 = *(const float4*)(ew + 0 * C_ + q);
    float4 w1 = *(const float4*)(ew + 1 * C_ + q);
    float4 w2 = *(const float4*)(ew + 2 * C_ + q);
    float4 w3 = *(const float4*)(ew + 3 * C_ + q);
    float4 bb = *(const float4*)(eb + q);
    float4 av = *(const float4*)(atoms + (size_t)src * C_ + q);
    float m0 = av.x + bb.x + ea.x * w0.x + ea.y * w1.x + ea.z * w2.x + ea.w * w3.x;
    float m1 = av.y + bb.y + ea.x * w0.y + ea.y * w1.y + ea.z * w2.y + ea.w * w3.y;
    float m2 = av.z + bb.z + ea.x * w0.z + ea.y * w1.z + ea.z * w2.z + ea.w * w3.z;
    float m3 = av.w + bb.w + ea.x * w0.w + ea.y * w1.w + ea.z * w2.w + ea.w * w3.w;
    float* base = aggr + (size_t)dst * C_ + q;
    atomicAdd(base + 0, fmaxf(m0, 0.f));
    atomicAdd(base + 1, fmaxf(m1, 0.f));
    atomicAdd(base + 2, fmaxf(m2, 0.f));
    atomicAdd(base + 3, fmaxf(m3, 0.f));
}

// --- weight transpose+cast: dst[rowBase+n][k] bf16 from W[l][k][n] fp32 ----
__global__ __launch_bounds__(256) void wt_kernel(const float* __restrict__ W,
                                                 short* __restrict__ Wt,
                                                 int K, int NC,
                                                 size_t lstride, int rowBase) {
    __shared__ short tile[64][65];
    int l = blockIdx.z;
    int k0 = blockIdx.y * 64, n0 = blockIdx.x * 64;
    const float* Wl = W + (size_t)l * K * NC;
    short* Wtl = Wt + (size_t)l * lstride + (size_t)rowBase * K;
    int t = threadIdx.x;
    int rr = t >> 4;
    int cc = (t & 15) * 4;
#pragma unroll
    for (int rep = 0; rep < 4; ++rep) {
        int r = rr + rep * 16;
        float4 v = *(const float4*)(Wl + (size_t)(k0 + r) * NC + n0 + cc);
        tile[cc + 0][r] = f2bf(v.x);
        tile[cc + 1][r] = f2bf(v.y);
        tile[cc + 2][r] = f2bf(v.z);
        tile[cc + 3][r] = f2bf(v.w);
    }
    __syncthreads();
#pragma unroll
    for (int rep = 0; rep < 4; ++rep) {
        int r = rr + rep * 16;
        short4v s;
        s.x = tile[r][cc + 0];
        s.y = tile[r][cc + 1];
        s.z = tile[r][cc + 2];
        s.w = tile[r][cc + 3];
        *(short4v*)(Wtl + (size_t)(n0 + r) * K + k0 + cc) = s;
    }
}

// ---------- proj cast: Pbf[l][m][d] bf16, padded to MP_ with zeros ---------
__global__ __launch_bounds__(256) void pcast_kernel(const float* __restrict__ proj,
                                                    short* __restrict__ Pbf) {
    int l = blockIdx.x;
    for (int idx = threadIdx.x; idx < MP_ * 64; idx += 256) {
        int m = idx >> 6, d = idx & 63;
        float v = (m < M_) ? proj[(size_t)l * M_ * 64 + m * 64 + d] : 0.f;
        Pbf[(size_t)l * MP_ * 64 + idx] = f2bf(v);
    }
}

// ---------------- MFMA bf16 matmul: Y = Xbf @ Wt (+epilogue) ---------------
// global_load_lds staging, XOR-swizzled unpadded LDS.
// EPI: 0=none, 1=gelu, 3=+R1b(bf16)
// OUT: 1=bf16 rm, 3=QKV split (NC=768: Q|K rm 256; V transposed, Yv)
template <int EPI, int OUT>
__global__ __launch_bounds__(256) void mfmm_kernel(
    const short* __restrict__ Xb, const short* __restrict__ Wt,
    const float* __restrict__ bias, const short* __restrict__ R1b,
    void* __restrict__ Yout, short* __restrict__ Yv, int K, int NC) {
    __shared__ short As[128][32];   // unpadded, 64B rows
    __shared__ short Bs[128][32];
    int tid = threadIdx.x;
    int rowBase = blockIdx.y * 128, colBase = blockIdx.x * 128;
    int lane = tid & 63;
    int wvu = __builtin_amdgcn_readfirstlane(tid >> 6);
    int wm = wvu & 1, wn = wvu >> 1;
    int quad = lane >> 4, l16 = lane & 15;
    int srow = lane >> 2;                       // row within 16-row chunk
    int sq = (lane & 3) ^ ((lane >> 3) & 3);    // swizzled global k-quad
    int csw = ((quad ^ ((l16 >> 1) & 3)) * 8);  // read column (shorts)
    const short* XpA = Xb + (size_t)(rowBase + wvu * 32 + srow) * K + sq * 8;
    const short* XpA2 = XpA + (size_t)16 * K;
    const short* WpB = Wt + (size_t)(colBase + wvu * 32 + srow) * K + sq * 8;
    const short* WpB2 = WpB + (size_t)16 * K;
    short* ldsA = &As[wvu * 32][0];
    short* ldsA2 = &As[wvu * 32 + 16][0];
    short* ldsB = &Bs[wvu * 32][0];
    short* ldsB2 = &Bs[wvu * 32 + 16][0];
    floatx4 acc[4][4];
#pragma unroll
    for (int i = 0; i < 4; ++i)
#pragma unroll
        for (int j = 0; j < 4; ++j)
            acc[i][j] = (floatx4){0.f, 0.f, 0.f, 0.f};
    for (int k0 = 0; k0 < K; k0 += 32) {
        __syncthreads();
        gl2lds16(XpA + k0, ldsA);
        gl2lds16(XpA2 + k0, ldsA2);
        gl2lds16(WpB + k0, ldsB);
        gl2lds16(WpB2 + k0, ldsB2);
        __syncthreads();
        short8 a[4], b[4];
#pragma unroll
        for (int mi = 0; mi < 4; ++mi)
            a[mi] = *(const short8*)&As[wm * 64 + mi * 16 + l16][csw];
#pragma unroll
        for (int ni = 0; ni < 4; ++ni)
            b[ni] = *(const short8*)&Bs[wn * 64 + ni * 16 + l16][csw];
#pragma unroll
        for (int mi = 0; mi < 4; ++mi)
#pragma unroll
            for (int ni = 0; ni < 4; ++ni)
                acc[mi][ni] = __builtin_amdgcn_mfma_f32_16x16x32_bf16(
                    a[mi], b[ni], acc[mi][ni], 0, 0, 0);
    }
    if (OUT == 3) {
        int region = colBase >> 8;   // 0=Q, 1=K, 2=V
        if (region < 2) {
            short* dst = (short*)Yout + (size_t)region * (size_t)TN * 256;
#pragma unroll
            for (int ni = 0; ni < 4; ++ni) {
                int cl = (colBase + wn * 64 + ni * 16 + l16) & 255;
#pragma unroll
                for (int mi = 0; mi < 4; ++mi) {
#pragma unroll
                    for (int r = 0; r < 4; ++r) {
                        int rowg = rowBase + wm * 64 + mi * 16 + quad * 4 + r;
                        dst[(size_t)rowg * 256 + cl] = f2bf(acc[mi][ni][r]);
                    }
                }
            }
        } else {
#pragma unroll
            for (int ni = 0; ni < 4; ++ni) {
                int cl = (colBase + wn * 64 + ni * 16 + l16) & 255;
                int hh = cl >> 6, dd = cl & 63;
#pragma unroll
                for (int mi = 0; mi < 4; ++mi) {
                    int rowg0 = rowBase + wm * 64 + mi * 16 + quad * 4;
                    int bb = rowg0 >> 9, ng = rowg0 & 511;
                    short4v pv;
#pragma unroll
                    for (int r = 0; r < 4; ++r) pv[r] = f2bf(acc[mi][ni][r]);
                    *(short4v*)(Yv + (((size_t)bb * 4 + hh) * 64 + dd) * 512 + ng) = pv;
                }
            }
        }
        return;
    }
#pragma unroll
    for (int ni = 0; ni < 4; ++ni) {
        int colg = colBase + wn * 64 + ni * 16 + l16;
        float bv = bias ? bias[colg] : 0.f;
#pragma unroll
        for (int mi = 0; mi < 4; ++mi) {
#pragma unroll
            for (int r = 0; r < 4; ++r) {
                int rowg = rowBase + wm * 64 + mi * 16 + quad * 4 + r;
                float y = acc[mi][ni][r] + bv;
                if (EPI == 1) y = gelu_exact(y);
                if (EPI == 3) y += bf2f(R1b[(size_t)rowg * NC + colg]);
                ((short*)Yout)[(size_t)rowg * NC + colg] = f2bf(y);
            }
        }
    }
}

// ------ MFMA matmul + fused row-LayerNorm epilogue (NC=256, 64-row tile) ---
// Y = LN(Xb@Wt + bias + Res)*g + beta  [+ Post if HAS_POST]  -> bf16
template <bool HAS_POST>
__global__ __launch_bounds__(256) void mfmm_ln_kernel(
    const short* __restrict__ Xb, const short* __restrict__ Wt,
    const float* __restrict__ bias, const short* __restrict__ Res,
    const short* __restrict__ Post, const float* __restrict__ g,
    const float* __restrict__ bta, short* __restrict__ Yout, int K) {
    __shared__ short As[64][32];    // 4 chunks
    __shared__ short Bs[256][32];   // 16 chunks
    __shared__ float redS[4][64];
    __shared__ float redS2[4][64];
    int tid = threadIdx.x;
    int rowBase = blockIdx.x * 64;
    int lane = tid & 63;
    int wvu = __builtin_amdgcn_readfirstlane(tid >> 6);
    int quad = lane >> 4, l16 = lane & 15;
    int srow = lane >> 2;
    int sq = (lane & 3) ^ ((lane >> 3) & 3);
    int csw = ((quad ^ ((l16 >> 1) & 3)) * 8);
    const short* Xp = Xb + (size_t)(rowBase + wvu * 16 + srow) * K + sq * 8;
    const short* Wp = Wt + (size_t)(wvu * 64 + srow) * K + sq * 8;
    short* ldsA = &As[wvu * 16][0];
    short* ldsB0 = &Bs[wvu * 64][0];
    short* ldsB1 = &Bs[wvu * 64 + 16][0];
    short* ldsB2 = &Bs[wvu * 64 + 32][0];
    short* ldsB3 = &Bs[wvu * 64 + 48][0];
    floatx4 acc[4][4];
#pragma unroll
    for (int i = 0; i < 4; ++i)
#pragma unroll
        for (int j = 0; j < 4; ++j)
            acc[i][j] = (floatx4){0.f, 0.f, 0.f, 0.f};
    for (int k0 = 0; k0 < K; k0 += 32) {
        __syncthreads();
        gl2lds16(Xp + k0, ldsA);
        gl2lds16(Wp + k0, ldsB0);
        gl2lds16(Wp + (size_t)16 * K + k0, ldsB1);
        gl2lds16(Wp + (size_t)32 * K + k0, ldsB2);
        gl2lds16(Wp + (size_t)48 * K + k0, ldsB3);
        __syncthreads();
        short8 a[4], b[4];
#pragma unroll
        for (int mi = 0; mi < 4; ++mi)
            a[mi] = *(const short8*)&As[mi * 16 + l16][csw];
#pragma unroll
        for (int ni = 0; ni < 4; ++ni)
            b[ni] = *(const short8*)&Bs[wvu * 64 + ni * 16 + l16][csw];
#pragma unroll
        for (int mi = 0; mi < 4; ++mi)
#pragma unroll
            for (int ni = 0; ni < 4; ++ni)
                acc[mi][ni] = __builtin_amdgcn_mfma_f32_16x16x32_bf16(
                    a[mi], b[ni], acc[mi][ni], 0, 0, 0);
    }
    // ---- epilogue: bias + residual, row stats, LN ----
    int cols[4];
    float gv[4], bv[4], biasv[4];
#pragma unroll
    for (int ni = 0; ni < 4; ++ni) {
        cols[ni] = wvu * 64 + ni * 16 + l16;
        gv[ni] = g[cols[ni]];
        bv[ni] = bta[cols[ni]];
        biasv[ni] = bias[cols[ni]];
    }
    float ps[4][4], ps2[4][4];
#pragma unroll
    for (int mi = 0; mi < 4; ++mi)
#pragma unroll
        for (int r = 0; r < 4; ++r) { ps[mi][r] = 0.f; ps2[mi][r] = 0.f; }
#pragma unroll
    for (int mi = 0; mi < 4; ++mi) {
#pragma unroll
        for (int r = 0; r < 4; ++r) {
            size_t rowg = rowBase + mi * 16 + quad * 4 + r;
#pragma unroll
            for (int ni = 0; ni < 4; ++ni) {
                float y = acc[mi][ni][r] + biasv[ni] +
                          bf2f(Res[rowg * 256 + cols[ni]]);
                acc[mi][ni][r] = y;
                ps[mi][r] += y;
                ps2[mi][r] += y * y;
            }
        }
    }
#pragma unroll
    for (int mask = 1; mask < 16; mask <<= 1) {
#pragma unroll
        for (int mi = 0; mi < 4; ++mi)
#pragma unroll
            for (int r = 0; r < 4; ++r) {
                ps[mi][r] += __shfl_xor(ps[mi][r], mask);
                ps2[mi][r] += __shfl_xor(ps2[mi][r], mask);
            }
    }
    __syncthreads();
    if (l16 == 0) {
#pragma unroll
        for (int mi = 0; mi < 4; ++mi)
#pragma unroll
            for (int r = 0; r < 4; ++r) {
                redS[wvu][mi * 16 + quad * 4 + r] = ps[mi][r];
                redS2[wvu][mi * 16 + quad * 4 + r] = ps2[mi][r];
            }
    }
    __syncthreads();
#pragma unroll
    for (int mi = 0; mi < 4; ++mi) {
#pragma unroll
        for (int r = 0; r < 4; ++r) {
            int rl = mi * 16 + quad * 4 + r;
            float s = redS[0][rl] + redS[1][rl] + redS[2][rl] + redS[3][rl];
            float s2 = redS2[0][rl] + redS2[1][rl] + redS2[2][rl] + redS2[3][rl];
            float mu = s * (1.f / 256.f);
            float var = s2 * (1.f / 256.f) - mu * mu;
            float inv = rsqrtf(var + LN_EPS_);
            size_t rowg = rowBase + rl;
#pragma unroll
            for (int ni = 0; ni < 4; ++ni) {
                float y = (acc[mi][ni][r] - mu) * inv * gv[ni] + bv[ni];
                if (HAS_POST) y += bf2f(Post[rowg * 256 + cols[ni]]);
                Yout[rowg * 256 + cols[ni]] = f2bf(y);
            }
        }
    }
}

// ------------- fallback fp32 tiled matmul (old path) -----------------------
template <bool IN_ADD, int EPI>
__global__ __launch_bounds__(256) void mm_kernel(
    const float* __restrict__ X, const float* __restrict__ X2,
    const float* __restrict__ W, const float* __restrict__ bias,
    const float* __restrict__ R1, const float* __restrict__ R2,
    float* __restrict__ Y, int K, int NC) {
    __shared__ float Xs[16][65];
    __shared__ float Ws[16][68];
    int tid = threadIdx.x;
    int tx = tid & 15, ty = tid >> 4;
    int rowBase = blockIdx.y * 64;
    int colBase = blockIdx.x * 64;
    int lr = tid >> 2;
    int lk = (tid & 3) << 2;
    int wk = tid >> 4;
    int wc = (tid & 15) << 2;
    const float* Xp = X + (size_t)(rowBase + lr) * K + lk;
    const float* X2p = IN_ADD ? (X2 + (size_t)(rowBase + lr) * K + lk) : X;
    const float* Wp = W + (size_t)wk * NC + colBase + wc;
    float acc[4][4] = {};
    for (int k0 = 0; k0 < K; k0 += 16) {
        float4 xv = *(const float4*)(Xp + k0);
        if (IN_ADD) {
            float4 x2 = *(const float4*)(X2p + k0);
            xv.x += x2.x; xv.y += x2.y; xv.z += x2.z; xv.w += x2.w;
        }
        float4 wv = *(const float4*)(Wp + (size_t)k0 * NC);
        __syncthreads();
        Xs[lk + 0][lr] = xv.x;
        Xs[lk + 1][lr] = xv.y;
        Xs[lk + 2][lr] = xv.z;
        Xs[lk + 3][lr] = xv.w;
        *(float4*)&Ws[wk][wc] = wv;
        __syncthreads();
#pragma unroll
        for (int kk = 0; kk < 16; ++kk) {
            float a[4], b[4];
#pragma unroll
            for (int i = 0; i < 4; ++i) a[i] = Xs[kk][ty * 4 + i];
#pragma unroll
            for (int j = 0; j < 4; ++j) b[j] = Ws[kk][tx * 4 + j];
#pragma unroll
            for (int i = 0; i < 4; ++i)
#pragma unroll
                for (int j = 0; j < 4; ++j) acc[i][j] = fmaf(a[i], b[j], acc[i][j]);
        }
    }
    int c0 = colBase + tx * 4;
    float4 bv = make_float4(0.f, 0.f, 0.f, 0.f);
    if (bias) bv = *(const float4*)(bias + c0);
#pragma unroll
    for (int i = 0; i < 4; ++i) {
        int r = rowBase + ty * 4 + i;
        float4 y;
        y.x = acc[i][0] + bv.x; y.y = acc[i][1] + bv.y;
        y.z = acc[i][2] + bv.z; y.w = acc[i][3] + bv.w;
        if (EPI == 1) {
            y.x = gelu_exact(y.x); y.y = gelu_exact(y.y);
            y.z = gelu_exact(y.z); y.w = gelu_exact(y.w);
        }
        if (EPI >= 2) {
            float4 r1 = *(const float4*)(R1 + (size_t)r * NC + c0);
            y.x += r1.x; y.y += r1.y; y.z += r1.z; y.w += r1.w;
        }
        if (EPI == 3) {
            float4 r2 = *(const float4*)(R2 + (size_t)r * NC + c0);
            y.x += r2.x; y.y += r2.y; y.z += r2.z; y.w += r2.w;
        }
        *(float4*)(Y + (size_t)r * NC + c0) = y;
    }
}

// fp32 LN fallback
__global__ __launch_bounds__(256) void ln_kernel(
    const float* __restrict__ X, const float* __restrict__ g,
    const float* __restrict__ bta, float* __restrict__ Y) {
    __shared__ float rs[4], rs2[4];
    __shared__ float mu_s, inv_s;
    int row = blockIdx.x, t = threadIdx.x;
    size_t off = (size_t)row * C_ + t;
    float v = X[off];
    float s = v, s2 = v * v;
#pragma unroll
    for (int o = 32; o > 0; o >>= 1) {
        s += __shfl_down(s, o);
        s2 += __shfl_down(s2, o);
    }
    int w = t >> 6, lane = t & 63;
    if (lane == 0) { rs[w] = s; rs2[w] = s2; }
    __syncthreads();
    if (t == 0) {
        float tot = rs[0] + rs[1] + rs[2] + rs[3];
        float tot2 = rs2[0] + rs2[1] + rs2[2] + rs2[3];
        float mu = tot * (1.f / C_);
        float var = tot2 * (1.f / C_) - mu * mu;
        mu_s = mu;
        inv_s = rsqrtf(var + LN_EPS_);
    }
    __syncthreads();
    Y[off] = (v - mu_s) * inv_s * g[t] + bta[t];
}

// ---------- MFMA Performer pass 1: ctxT[bh][d][m], ksum[bh][m] -------------
__global__ __launch_bounds__(256) void p1m_kernel(
    const short* __restrict__ Kbf, const short* __restrict__ VbfT,
    const short* __restrict__ Pbf, short* __restrict__ ctxT,
    float* __restrict__ ksum) {
    int mt = blockIdx.x;
    int bh = blockIdx.y;
    int b = bh >> 2, h = bh & 3;
    __shared__ short Ps[64][72];
    __shared__ short Ks[64][72];
    __shared__ short VTs[64][72];
    __shared__ short Ss[64][72];
    __shared__ float kred[4][64];
    int tid = threadIdx.x;
    int w = tid >> 6, lane = tid & 63;
    int quad = lane >> 4, l16 = lane & 15;
    int lr = tid >> 2, lb = (tid & 3) << 4;
    {
        const short* p = Pbf + ((size_t)(mt * 64 + lr)) * 64 + lb;
        *(short8*)&Ps[lr][lb] = *(const short8*)p;
        *(short8*)&Ps[lr][lb + 8] = *(const short8*)(p + 8);
    }
    floatx4 cacc[4];
#pragma unroll
    for (int i = 0; i < 4; ++i) cacc[i] = (floatx4){0.f, 0.f, 0.f, 0.f};
    float kacc[4] = {0.f, 0.f, 0.f, 0.f};
    size_t kbase = ((size_t)(b * 512)) * 256 + h * 64;
    size_t vbase = ((size_t)(bh * 64)) * 512;
    for (int nt = 0; nt < 8; ++nt) {
        __syncthreads();
        {
            const short* kp = Kbf + kbase + (size_t)(nt * 64 + lr) * 256 + lb;
            *(short8*)&Ks[lr][lb] = *(const short8*)kp;
            *(short8*)&Ks[lr][lb + 8] = *(const short8*)(kp + 8);
            const short* vp = VbfT + vbase + (size_t)lr * 512 + nt * 64 + lb;
            *(short8*)&VTs[lr][lb] = *(const short8*)vp;
            *(short8*)&VTs[lr][lb + 8] = *(const short8*)(vp + 8);
        }
        __syncthreads();
        floatx4 sa[4];
#pragma unroll
        for (int mi = 0; mi < 4; ++mi) sa[mi] = (floatx4){0.f, 0.f, 0.f, 0.f};
#pragma unroll
        for (int kt = 0; kt < 2; ++kt) {
            short8 a = *(const short8*)&Ks[w * 16 + l16][kt * 32 + quad * 8];
#pragma unroll
            for (int mi = 0; mi < 4; ++mi) {
                short8 bq = *(const short8*)&Ps[mi * 16 + l16][kt * 32 + quad * 8];
                sa[mi] = __builtin_amdgcn_mfma_f32_16x16x32_bf16(a, bq, sa[mi], 0, 0, 0);
            }
        }
#pragma unroll
        for (int mi = 0; mi < 4; ++mi) {
            int mg = mt * 64 + mi * 16 + l16;
            short4v sv;
            float kl = 0.f;
#pragma unroll
            for (int r = 0; r < 4; ++r) {
                float v = (mg < M_) ? (fmaxf(sa[mi][r], 0.f) + EPSK_) : 0.f;
                sv[r] = f2bf(v);
                kl += v;
            }
            kacc[mi] += kl;
            *(short4v*)&Ss[mi * 16 + l16][w * 16 + quad * 4] = sv;
        }
        __syncthreads();
#pragma unroll
        for (int kt = 0; kt < 2; ++kt) {
            short8 a = *(const short8*)&Ss[w * 16 + l16][kt * 32 + quad * 8];
#pragma unroll
            for (int di = 0; di < 4; ++di) {
                short8 bv = *(const short8*)&VTs[di * 16 + l16][kt * 32 + quad * 8];
                cacc[di] = __builtin_amdgcn_mfma_f32_16x16x32_bf16(a, bv, cacc[di], 0, 0, 0);
            }
        }
    }
    size_t cbase = ((size_t)bh * 64) * MP_ + mt * 64;
#pragma unroll
    for (int di = 0; di < 4; ++di) {
        int d = di * 16 + l16;
        short4v cv;
#pragma unroll
        for (int r = 0; r < 4; ++r) cv[r] = f2bf(cacc[di][r]);
        *(short4v*)(ctxT + cbase + (size_t)d * MP_ + w * 16 + quad * 4) = cv;
    }
#pragma unroll
    for (int mi = 0; mi < 4; ++mi) {
        kacc[mi] += __shfl_down(kacc[mi], 32);
        kacc[mi] += __shfl_down(kacc[mi], 16);
    }
    if (lane < 16) {
#pragma unroll
        for (int mi = 0; mi < 4; ++mi) kred[w][mi * 16 + lane] = kacc[mi];
    }
    __syncthreads();
    if (tid < 64)
        ksum[(size_t)bh * MP_ + mt * 64 + tid] =
            kred[0][tid] + kred[1][tid] + kred[2][tid] + kred[3][tid];
}

// ---------- MFMA Performer pass 2: attbf = bf16((qp@ctx)/(qp@ksum)) --------
__global__ __launch_bounds__(256) void p2m_kernel(
    const short* __restrict__ Qbf, const short* __restrict__ Pbf,
    const short* __restrict__ ctxT, const float* __restrict__ ksum,
    short* __restrict__ attbf) {
    int nt = blockIdx.x;
    int bh = blockIdx.y;
    int b = bh >> 2, h = bh & 3;
    __shared__ short Qs[64][72];
    __shared__ short Ps[64][72];
    __shared__ short CTs[64][72];
    __shared__ short Ss[64][72];
    __shared__ float kss[64];
    __shared__ float dredS[64];
    __shared__ float dinvS[64];
    int tid = threadIdx.x;
    int w = tid >> 6, lane = tid & 63;
    int quad = lane >> 4, l16 = lane & 15;
    int lr = tid >> 2, lb = (tid & 3) << 4;
    size_t qbase = ((size_t)(b * 512)) * 256 + h * 64;
    {
        const short* qp = Qbf + qbase + (size_t)(nt * 64 + lr) * 256 + lb;
        *(short8*)&Qs[lr][lb] = *(const short8*)qp;
        *(short8*)&Qs[lr][lb + 8] = *(const short8*)(qp + 8);
    }
    floatx4 aacc[4];
#pragma unroll
    for (int i = 0; i < 4; ++i) aacc[i] = (floatx4){0.f, 0.f, 0.f, 0.f};
    float dd[4] = {0.f, 0.f, 0.f, 0.f};
    size_t cb = ((size_t)bh * 64) * MP_;
    for (int mt = 0; mt < 5; ++mt) {
        __syncthreads();
        {
            const short* p = Pbf + ((size_t)(mt * 64 + lr)) * 64 + lb;
            *(short8*)&Ps[lr][lb] = *(const short8*)p;
            *(short8*)&Ps[lr][lb + 8] = *(const short8*)(p + 8);
            const short* cp = ctxT + cb + (size_t)lr * MP_ + mt * 64 + lb;
            *(short8*)&CTs[lr][lb] = *(const short8*)cp;
            *(short8*)&CTs[lr][lb + 8] = *(const short8*)(cp + 8);
        }
        if (tid < 64) kss[tid] = ksum[(size_t)bh * MP_ + mt * 64 + tid];
        __syncthreads();
        floatx4 sa[4];
#pragma unroll
        for (int mi = 0; mi < 4; ++mi) sa[mi] = (floatx4){0.f, 0.f, 0.f, 0.f};
#pragma unroll
        for (int kt = 0; kt < 2; ++kt) {
            short8 a = *(const short8*)&Qs[w * 16 + l16][kt * 32 + quad * 8];
#pragma unroll
            for (int mi = 0; mi < 4; ++mi) {
                short8 bq = *(const short8*)&Ps[mi * 16 + l16][kt * 32 + quad * 8];
                sa[mi] = __builtin_amdgcn_mfma_f32_16x16x32_bf16(a, bq, sa[mi], 0, 0, 0);
            }
        }
#pragma unroll
        for (int mi = 0; mi < 4; ++mi) {
            int mg = mt * 64 + mi * 16 + l16;
            float ksv = kss[mi * 16 + l16];
#pragma unroll
            for (int r = 0; r < 4; ++r) {
                float v = (mg < M_) ? (fmaxf(sa[mi][r], 0.f) + EPSK_) : 0.f;
                Ss[w * 16 + quad * 4 + r][mi * 16 + l16] = f2bf(v);
                dd[r] += v * ksv;
            }
        }
        __syncthreads();
#pragma unroll
        for (int kt = 0; kt < 2; ++kt) {
            short8 a = *(const short8*)&Ss[w * 16 + l16][kt * 32 + quad * 8];
#pragma unroll
            for (int di = 0; di < 4; ++di) {
                short8 bv = *(const short8*)&CTs[di * 16 + l16][kt * 32 + quad * 8];
                aacc[di] = __builtin_amdgcn_mfma_f32_16x16x32_bf16(a, bv, aacc[di], 0, 0, 0);
            }
        }
    }
#pragma unroll
    for (int r = 0; r < 4; ++r) {
        dd[r] += __shfl_xor(dd[r], 1);
        dd[r] += __shfl_xor(dd[r], 2);
        dd[r] += __shfl_xor(dd[r], 4);
        dd[r] += __shfl_xor(dd[r], 8);
    }
    if (l16 == 0) {
#pragma unroll
        for (int r = 0; r < 4; ++r) dredS[w * 16 + quad * 4 + r] = dd[r];
    }
    __syncthreads();
    if (tid < 64) dinvS[tid] = 1.f / dredS[tid];
    __syncthreads();
#pragma unroll
    for (int di = 0; di < 4; ++di) {
        int d = di * 16 + l16;
#pragma unroll
        for (int r = 0; r < 4; ++r) {
            int n = w * 16 + quad * 4 + r;
            attbf[((size_t)(b * 512 + nt * 64 + n)) * 256 + h * 64 + d] =
                f2bf(aacc[di][r] * dinvS[n]);
        }
    }
}

// ---------------- fp32 Performer fallbacks (old path) ----------------------
__global__ __launch_bounds__(256) void p1_kernel(
    const float* __restrict__ kbuf, const float* __restrict__ vbuf,
    const float* __restrict__ proj, float* __restrict__ ctx,
    float* __restrict__ ksum) {
    int mt = blockIdx.x;
    int bh = blockIdx.y;
    int b = bh >> 2, h = bh & 3;
    __shared__ float Pt[64][65];
    __shared__ float KV[64][65];
    __shared__ float S[64][65];
    int tid = threadIdx.x;
    int tx = tid & 15, ty = tid >> 4;
    for (int idx = tid; idx < 4096; idx += 256) {
        int r = idx >> 6, c = idx & 63;
        int mg = mt * 64 + r;
        Pt[r][c] = (mg < M_) ? proj[mg * DH_ + c] : 0.f;
    }
    float cacc[4][4] = {};
    float ksacc = 0.f;
    size_t base = ((size_t)b * N_) * C_ + h * DH_;
    for (int nt = 0; nt < 8; ++nt) {
        __syncthreads();
        for (int idx = tid; idx < 4096; idx += 256) {
            int r = idx >> 6, c = idx & 63;
            KV[r][c] = kbuf[base + (size_t)(nt * 64 + r) * C_ + c];
        }
        __syncthreads();
        float s[4][4] = {};
        for (int dd = 0; dd < 64; ++dd) {
            float a[4], bq[4];
#pragma unroll
            for (int i = 0; i < 4; ++i) a[i] = KV[ty * 4 + i][dd];
#pragma unroll
            for (int j = 0; j < 4; ++j) bq[j] = Pt[16 * j + tx][dd];
#pragma unroll
            for (int i = 0; i < 4; ++i)
#pragma unroll
                for (int j = 0; j < 4; ++j) s[i][j] = fmaf(a[i], bq[j], s[i][j]);
        }
        __syncthreads();
#pragma unroll
        for (int i = 0; i < 4; ++i)
#pragma unroll
            for (int j = 0; j < 4; ++j) {
                int mg = mt * 64 + 16 * j + tx;
                S[ty * 4 + i][16 * j + tx] =
                    (mg < M_) ? (fmaxf(s[i][j], 0.f) + EPSK_) : 0.f;
            }
        for (int idx = tid; idx < 4096; idx += 256) {
            int r = idx >> 6, c = idx & 63;
            KV[r][c] = vbuf[base + (size_t)(nt * 64 + r) * C_ + c];
        }
        __syncthreads();
        for (int nn = 0; nn < 64; ++nn) {
            float sm[4], vd[4];
#pragma unroll
            for (int i = 0; i < 4; ++i) sm[i] = S[nn][ty * 4 + i];
#pragma unroll
            for (int j = 0; j < 4; ++j) vd[j] = KV[nn][tx * 4 + j];
#pragma unroll
            for (int i = 0; i < 4; ++i)
#pragma unroll
                for (int j = 0; j < 4; ++j) cacc[i][j] = fmaf(sm[i], vd[j], cacc[i][j]);
        }
        if (tid < 64) {
            for (int nn = 0; nn < 64; ++nn) ksacc += S[nn][tid];
        }
    }
    float* cp = ctx + ((size_t)bh * MP_ + mt * 64) * DH_;
#pragma unroll
    for (int i = 0; i < 4; ++i)
#pragma unroll
        for (int j = 0; j < 4; ++j)
            cp[(ty * 4 + i) * DH_ + tx * 4 + j] = cacc[i][j];
    if (tid < 64) ksum[bh * MP_ + mt * 64 + tid] = ksacc;
}

__global__ __launch_bounds__(256) void p2_kernel(
    const float* __restrict__ qbuf, const float* __restrict__ proj,
    const float* __restrict__ ctx, const float* __restrict__ ksum,
    float* __restrict__ attout) {
    int nt = blockIdx.x;
    int bh = blockIdx.y;
    int b = bh >> 2, h = bh & 3;
    __shared__ float Qt[64][65];
    __shared__ float PC[64][65];
    __shared__ float S[64][65];
    __shared__ float ks[64], dinv[64];
    int tid = threadIdx.x;
    int tx = tid & 15, ty = tid >> 4;
    size_t base = ((size_t)b * N_) * C_ + h * DH_;
    for (int idx = tid; idx < 4096; idx += 256) {
        int r = idx >> 6, c = idx & 63;
        Qt[r][c] = qbuf[base + (size_t)(nt * 64 + r) * C_ + c];
    }
    float aacc[4][4] = {};
    float dacc = 0.f;
    for (int mt = 0; mt < 5; ++mt) {
        __syncthreads();
        for (int idx = tid; idx < 4096; idx += 256) {
            int r = idx >> 6, c = idx & 63;
            int mg = mt * 64 + r;
            PC[r][c] = (mg < M_) ? proj[mg * DH_ + c] : 0.f;
        }
        if (tid < 64) ks[tid] = ksum[bh * MP_ + mt * 64 + tid];
        __syncthreads();
        float s[4][4] = {};
        for (int dd = 0; dd < 64; ++dd) {
            float a[4], bq[4];
#pragma unroll
            for (int i = 0; i < 4; ++i) a[i] = Qt[ty * 4 + i][dd];
#pragma unroll
            for (int j = 0; j < 4; ++j) bq[j] = PC[16 * j + tx][dd];
#pragma unroll
            for (int i = 0; i < 4; ++i)
#pragma unroll
                for (int j = 0; j < 4; ++j) s[i][j] = fmaf(a[i], bq[j], s[i][j]);
        }
        __syncthreads();
#pragma unroll
        for (int i = 0; i < 4; ++i)
#pragma unroll
            for (int j = 0; j < 4; ++j) {
                int mg = mt * 64 + 16 * j + tx;
                S[ty * 4 + i][16 * j + tx] =
                    (mg < M_) ? (fmaxf(s[i][j], 0.f) + EPSK_) : 0.f;
            }
        for (int idx = tid; idx < 4096; idx += 256) {
            int r = idx >> 6, c = idx & 63;
            PC[r][c] = ctx[((size_t)bh * MP_ + mt * 64 + r) * DH_ + c];
        }
        __syncthreads();
        for (int mm = 0; mm < 64; ++mm) {
            float sm[4], cd[4];
#pragma unroll
            for (int i = 0; i < 4; ++i) sm[i] = S[ty * 4 + i][mm];
#pragma unroll
            for (int j = 0; j < 4; ++j) cd[j] = PC[mm][tx * 4 + j];
#pragma unroll
            for (int i = 0; i < 4; ++i)
#pragma unroll
                for (int j = 0; j < 4; ++j) aacc[i][j] = fmaf(sm[i], cd[j], aacc[i][j]);
        }
        if (tid < 64) {
            for (int mm = 0; mm < 64; ++mm) dacc = fmaf(S[tid][mm], ks[mm], dacc);
        }
    }
    __syncthreads();
    if (tid < 64) dinv[tid] = 1.f / dacc;
    __syncthreads();
#pragma unroll
    for (int i = 0; i < 4; ++i) {
        int n = ty * 4 + i;
        float di = dinv[n];
        float4 y = make_float4(aacc[i][0] * di, aacc[i][1] * di,
                               aacc[i][2] * di, aacc[i][3] * di);
        *(float4*)(attout + base + (size_t)(nt * 64 + n) * C_ + tx * 4) = y;
    }
}

// -------------------- mean pool (bf16 in, fp32 out) ------------------------
__global__ __launch_bounds__(256) void pool_kernel(const short* __restrict__ abf,
                                                   float* __restrict__ out) {
    int b = blockIdx.x;
    int c = threadIdx.x;
    const short* p = abf + (size_t)b * N_ * C_ + c;
    float s = 0.f;
    for (int n = 0; n < N_; ++n) s += bf2f(p[(size_t)n * C_]);
    out[b * C_ + c] = s * (1.f / 512.f);
}

__global__ __launch_bounds__(256) void poolf_kernel(const float* __restrict__ atoms,
                                                    float* __restrict__ out) {
    int b = blockIdx.x;
    int c = threadIdx.x;
    const float* p = atoms + (size_t)b * N_ * C_ + c;
    float s = 0.f;
    for (int n = 0; n < N_; ++n) s += p[(size_t)n * C_];
    out[b * C_ + c] = s * (1.f / 512.f);
}

extern "C" void kernel_launch(void* const* d_in, const int* in_sizes, int n_in,
                              void* d_out, int out_size, void* d_ws, size_t ws_size,
                              hipStream_t stream) {
    (void)in_sizes; (void)n_in; (void)out_size;
    const float* x = (const float*)d_in[0];
    const float* edge_attr = (const float*)d_in[1];
    const int* edge_index = (const int*)d_in[2];
    const float* node_w = (const float*)d_in[4];
    const float* node_b = (const float*)d_in[5];
    const float* edge_w = (const float*)d_in[6];
    const float* edge_b = (const float*)d_in[7];
    const float* gine_w1 = (const float*)d_in[8];
    const float* gine_b1 = (const float*)d_in[9];
    const float* gine_w2 = (const float*)d_in[10];
    const float* gine_b2 = (const float*)d_in[11];
    const float* q_w = (const float*)d_in[12];
    const float* k_w = (const float*)d_in[13];
    const float* v_w = (const float*)d_in[14];
    const float* o_w = (const float*)d_in[15];
    const float* o_b = (const float*)d_in[16];
    const float* proj = (const float*)d_in[17];
    const float* n1g = (const float*)d_in[18];
    const float* n1b = (const float*)d_in[19];
    const float* n2g = (const float*)d_in[20];
    const float* n2b = (const float*)d_in[21];
    const float* n3g = (const float*)d_in[22];
    const float* n3b = (const float*)d_in[23];
    const float* mw1 = (const float*)d_in[24];
    const float* mb1 = (const float*)d_in[25];
    const float* mw2 = (const float*)d_in[26];
    const float* mb2 = (const float*)d_in[27];

    const size_t SZ = (size_t)TN * C_;   // 8,388,608
    float* ws = (float*)d_ws;
    float* A     = ws;                               // fp32 atoms (fallback only)
    short* Abf   = (short*)(ws + SZ);
    short* X1bf  = (short*)(ws + SZ + SZ / 2);       // also t2bf
    short* t2bf  = X1bf;
    short* t1bf  = (short*)(ws + 2 * SZ);            // also ATTbf
    short* ATTbf = t1bf;
    short* HLbf  = (short*)(ws + 2 * SZ + SZ / 2);
    short* Qbf   = (short*)(ws + 3 * SZ);
    short* Kbf   = (short*)(ws + 3 * SZ + SZ / 2);
    short* VbfT  = (short*)(ws + 4 * SZ);
    short* ctxTb = (short*)(ws + 4 * SZ + SZ / 2);
    float* KS2   = (float*)(ctxTb + (size_t)256 * 64 * MP_);
    short* SUMbf = (short*)(ws + 5 * SZ);

    int* deg    = (int*)(ws + 6 * SZ);
    int* offs   = deg + TN;
    int* cursor = offs + TN + 1;
    int* esrc   = cursor + TN;
    float* easrt = (float*)(((uintptr_t)(esrc + E_) + 15) & ~(uintptr_t)15);
    short* WTg1  = (short*)(easrt + (size_t)4 * E_);
    short* WTg2  = WTg1 + (size_t)5 * 65536;
    short* WTqkv = WTg2 + (size_t)5 * 65536;
    short* WTo   = WTqkv + (size_t)5 * 196608;
    short* WTm1  = WTo + (size_t)5 * 65536;
    short* WTm2  = WTm1 + (size_t)5 * 131072;
    short* Pbf   = WTm2 + (size_t)5 * 131072;
    size_t need = 6 * SZ * sizeof(float) +
                  (size_t)(3 * TN + 1 + E_) * sizeof(int) + 16 +
                  (size_t)4 * E_ * sizeof(float) +
                  ((size_t)5 * (3 * 65536 + 196608 + 2 * 131072 + MP_ * 64)) *
                      sizeof(short);
    bool full = ws_size >= need;

    dim3 gm256(2, 256), gm512(4, 256), gm768(6, 256);
    dim3 g256(4, 512), g512(8, 512);

    embed_kernel<<<TN, 256, 0, stream>>>(x, node_w, node_b, A, Abf);
    if (full) {
        hipMemsetAsync(deg, 0, TN * sizeof(int), stream);
        count_kernel<<<E_ / 256, 256, 0, stream>>>(edge_index, deg);
        scan_kernel<<<1, 1024, 0, stream>>>(deg, offs, cursor);
        fill_kernel<<<E_ / 256, 256, 0, stream>>>(edge_index, edge_attr, cursor,
                                                  esrc, easrt);
        wt_kernel<<<dim3(4, 4, L_), 256, 0, stream>>>(gine_w1, WTg1, 256, 256, 65536, 0);
        wt_kernel<<<dim3(4, 4, L_), 256, 0, stream>>>(gine_w2, WTg2, 256, 256, 65536, 0);
        wt_kernel<<<dim3(4, 4, L_), 256, 0, stream>>>(q_w, WTqkv, 256, 256, 196608, 0);
        wt_kernel<<<dim3(4, 4, L_), 256, 0, stream>>>(k_w, WTqkv, 256, 256, 196608, 256);
        wt_kernel<<<dim3(4, 4, L_), 256, 0, stream>>>(v_w, WTqkv, 256, 256, 196608, 512);
        wt_kernel<<<dim3(4, 4, L_), 256, 0, stream>>>(o_w, WTo, 256, 256, 65536, 0);
        wt_kernel<<<dim3(8, 4, L_), 256, 0, stream>>>(mw1, WTm1, 256, 512, 131072, 0);
        wt_kernel<<<dim3(4, 8, L_), 256, 0, stream>>>(mw2, WTm2, 512, 256, 131072, 0);
        pcast_kernel<<<L_, 256, 0, stream>>>(proj, Pbf);
    }
    for (int l = 0; l < L_; ++l) {
        if (full) {
            gather_kernel<<<TN / 4, 256, 0, stream>>>(Abf, offs, esrc, easrt,
                                                      edge_w, edge_b, X1bf);
            // t1 = gelu(X1 @ g1 + b1)
            mfmm_kernel<1, 1><<<gm256, 256, 0, stream>>>(
                X1bf, WTg1 + (size_t)l * 65536, gine_b1 + l * 256,
                nullptr, t1bf, nullptr, 256, 256);
            // HL = LN1(t1 @ g2 + b2 + Abf)   [fused]
            mfmm_ln_kernel<false><<<TN / 64, 256, 0, stream>>>(
                t1bf, WTg2 + (size_t)l * 65536, gine_b2 + l * 256,
                Abf, nullptr, n1g + l * 256, n1b + l * 256, HLbf, 256);
            // QKV fused
            mfmm_kernel<0, 3><<<gm768, 256, 0, stream>>>(
                Abf, WTqkv + (size_t)l * 196608, nullptr,
                nullptr, Qbf, VbfT, 256, 768);
            p1m_kernel<<<dim3(5, 256), 256, 0, stream>>>(
                Kbf, VbfT, Pbf + (size_t)l * MP_ * 64, ctxTb, KS2);
            p2m_kernel<<<dim3(8, 256), 256, 0, stream>>>(
                Qbf, Pbf + (size_t)l * MP_ * 64, ctxTb, KS2, ATTbf);
            // SUM = LN2(ATT @ o_w + o_b + Abf) + HL   [fused]
            mfmm_ln_kernel<true><<<TN / 64, 256, 0, stream>>>(
                ATTbf, WTo + (size_t)l * 65536, o_b + l * 256,
                Abf, HLbf, n2g + l * 256, n2b + l * 256, SUMbf, 256);
            // t2 = gelu(SUM @ m1 + b1)  [NC=512]
            mfmm_kernel<1, 1><<<gm512, 256, 0, stream>>>(
                SUMbf, WTm1 + (size_t)l * 131072, mb1 + l * 512,
                nullptr, t2bf, nullptr, 256, 512);
            // Abf = LN3(t2 @ m2 + b2 + SUM)  [K=512, fused]
            mfmm_ln_kernel<false><<<TN / 64, 256, 0, stream>>>(
                t2bf, WTm2 + (size_t)l * 131072, mb2 + l * 256,
                SUMbf, nullptr, n3g + l * 256, n3b + l * 256, Abf, 512);
        } else {
            float* AGf = A + SZ;
            float* Tf = AGf + SZ;
            float* HLf = Tf + 2 * SZ;
            float* Vbf2 = HLf + SZ;
            float* Qf = AGf;
            float* Kf = Tf;
            float* CTXf = Tf + SZ;
            float* KSf = CTXf + (size_t)256 * MP_ * DH_;
            hipMemsetAsync(AGf, 0, SZ * sizeof(float), stream);
            scatter_kernel<<<E_ * 64 / 256, 256, 0, stream>>>(A, edge_attr, edge_index,
                                                              edge_w, edge_b, AGf);
            mm_kernel<true, 1><<<g256, 256, 0, stream>>>(A, AGf, gine_w1 + l * 65536,
                                                         gine_b1 + l * 256, nullptr,
                                                         nullptr, Tf, 256, 256);
            mm_kernel<false, 2><<<g256, 256, 0, stream>>>(Tf, nullptr, gine_w2 + l * 65536,
                                                          gine_b2 + l * 256, A, nullptr,
                                                          HLf, 256, 256);
            ln_kernel<<<TN, 256, 0, stream>>>(HLf, n1g + l * 256, n1b + l * 256, HLf);
            mm_kernel<false, 0><<<g256, 256, 0, stream>>>(A, nullptr, q_w + l * 65536,
                                                          nullptr, nullptr, nullptr,
                                                          Qf, 256, 256);
            mm_kernel<false, 0><<<g256, 256, 0, stream>>>(A, nullptr, k_w + l * 65536,
                                                          nullptr, nullptr, nullptr,
                                                          Kf, 256, 256);
            mm_kernel<false, 0><<<g256, 256, 0, stream>>>(A, nullptr, v_w + l * 65536,
                                                          nullptr, nullptr, nullptr,
                                                          Vbf2, 256, 256);
            p1_kernel<<<dim3(5, 256), 256, 0, stream>>>(Kf, Vbf2, proj + l * (M_ * DH_),
                                                        CTXf, KSf);
            p2_kernel<<<dim3(8, 256), 256, 0, stream>>>(Qf, proj + l * (M_ * DH_),
                                                        CTXf, KSf, Kf);
            mm_kernel<false, 2><<<g256, 256, 0, stream>>>(Kf, nullptr, o_w + l * 65536,
                                                          o_b + l * 256, A, nullptr,
                                                          Qf, 256, 256);
            ln_kernel<<<TN, 256, 0, stream>>>(Qf, n2g + l * 256, n2b + l * 256, Qf);
            mm_kernel<true, 1><<<g512, 256, 0, stream>>>(HLf, Qf, mw1 + l * 131072,
                                                         mb1 + l * 512, nullptr, nullptr,
                                                         Tf, 256, 512);
            mm_kernel<false, 3><<<g256, 256, 0, stream>>>(Tf, nullptr, mw2 + l * 131072,
                                                          mb2 + l * 256, HLf, Qf,
                                                          Vbf2, 512, 256);
            ln_kernel<<<TN, 256, 0, stream>>>(Vbf2, n3g + l * 256, n3b + l * 256, A);
        }
    }
    if (full)
        pool_kernel<<<B_, 256, 0, stream>>>(Abf, (float*)d_out);
    else
        poolf_kernel<<<B_, 256, 0, stream>>>(A, (float*)d_out);
}